// Round 7
// baseline (2367.816 us; speedup 1.0000x reference)
//
#include <hip/hip_runtime.h>
#include <hip/hip_fp16.h>
#include <math.h>

typedef __bf16   bf16x8 __attribute__((ext_vector_type(8)));
typedef _Float16 f16x8  __attribute__((ext_vector_type(8)));
typedef float    f32x4  __attribute__((ext_vector_type(4)));

#define AH  264              // act plane stride (bf16)
#define TOT 589824           // staged weight elems (hi); lo at +TOT

// staged ws layout (bf16, [n][k] transposed, zero-padded K tails)
#define OFF_W0T   0          // [256][64]
#define OFF_WHT   16384      // 4 x [256][256]
#define OFF_W5AT  278528     // [256][256]
#define OFF_W5BT  344064     // [256][64]
#define OFF_W6T   360448     // [256][256]
#define OFF_W7T   425984     // [256][256]
#define OFF_WFT   491520     // [256][256]
#define OFF_WMAT  557056     // [128][256]

__global__ void prep_weights(const float* __restrict__ W0, const float* __restrict__ Wh,
                             const float* __restrict__ W5, const float* __restrict__ W6,
                             const float* __restrict__ W7, const float* __restrict__ Wf,
                             const float* __restrict__ Wm, __bf16* __restrict__ ws) {
  int idx = blockIdx.x * blockDim.x + threadIdx.x;
  if (idx >= TOT) return;
  float v = 0.f;
  if (idx < OFF_WHT)        { int j = idx;            int n=j>>6, k=j&63;   v = (k<60)? W0[k*256+n] : 0.f; }
  else if (idx < OFF_W5AT)  { int j = idx - OFF_WHT;  int i=j>>16, r=j&65535, n=r>>8, k=r&255; v = Wh[i*65536+k*256+n]; }
  else if (idx < OFF_W5BT)  { int j = idx - OFF_W5AT; int n=j>>8, k=j&255;  v = W5[k*256+n]; }
  else if (idx < OFF_W6T)   { int j = idx - OFF_W5BT; int n=j>>6, k=j&63;   v = (k<60)? W5[(256+k)*256+n] : 0.f; }
  else if (idx < OFF_W7T)   { int j = idx - OFF_W6T;  int n=j>>8, k=j&255;  v = W6[k*256+n]; }
  else if (idx < OFF_WFT)   { int j = idx - OFF_W7T;  int n=j>>8, k=j&255;  v = W7[k*256+n]; }
  else if (idx < OFF_WMAT)  { int j = idx - OFF_WFT;  int n=j>>8, k=j&255;  v = Wf[k*256+n]; }
  else                      { int j = idx - OFF_WMAT; int n=j>>8, k=j&255;  v = Wm[k*128+n]; }
  __bf16 hi = (__bf16)v;
  ws[idx] = hi;
  ws[TOT + idx] = (__bf16)(v - (float)hi);
}

#define MFMA16(A,B,C) __builtin_amdgcn_mfma_f32_16x16x32_bf16((A),(B),(C),0,0,0)

// ======== HALF=1 layer: 2m x 4n wave decomposition (M=64) ========
// wave = (mi=wave>>2)*32 rows x (ni=wave&3)*(NT*16) cols. Each wave reads only
// its 32 A-rows from LDS (half the act traffic / bank conflicts of all-M x 1/8N
// -- measured conflicts 8.6e7 -> 4.5e7). Weight loads A/B double-buffered
// (prefetch kc+1 before kc's MFMA block); NKC templated -> full unroll.
// Live regs ~112 (acc 32 + 2x wbuf 64 + act 16): needs the 128-reg budget that
// amdgpu_waves_per_eu(4,4) unlocks (R6 without it: allocator targeted 64 regs
// for unreachable 8-wave occupancy -> 487 MB scratch spill traffic).
// Per-element accumulation order: kc ascending; a_h*b_h, a_h*b_l, a_l*b_h
// -> bit-identical to all prior versions.
template<int NT, int NKC>
__device__ __forceinline__ void layer_row(__bf16* aHi, __bf16* aLo, const __half* pxh,
    const __bf16* __restrict__ wHi, const __bf16* __restrict__ wLo, int kStr,
    const __bf16* __restrict__ xHi, const __bf16* __restrict__ xLo,  // px weights or null
    const float* __restrict__ bias, const float* __restrict__ pdW,
    bool relu, int tid) {
  const int wave = tid >> 6, lane = tid & 63;
  const int lm = lane & 15, kq = lane >> 4;
  const int mBase = (wave >> 2) * 32;          // mi in {0,1}
  const int nBase = (wave & 3) * (NT * 16);    // ni in {0..3}
  f32x4 acc[2][NT];
#pragma unroll
  for (int mt = 0; mt < 2; ++mt)
#pragma unroll
    for (int nt = 0; nt < NT; ++nt)
#pragma unroll
      for (int e = 0; e < 4; ++e) acc[mt][nt][e] = 0.f;

  const int kb0 = kq * 8;
  const int ar = (mBase + lm) * AH + kb0;

#define MFMA_BLK(BH,BL,A0H,A0L,A1H,A1L)                       \
    _Pragma("unroll")                                         \
    for (int nt = 0; nt < NT; ++nt) {                         \
      acc[0][nt] = MFMA16(A0H, BH[nt], acc[0][nt]);           \
      acc[0][nt] = MFMA16(A0H, BL[nt], acc[0][nt]);           \
      acc[0][nt] = MFMA16(A0L, BH[nt], acc[0][nt]);           \
      acc[1][nt] = MFMA16(A1H, BH[nt], acc[1][nt]);           \
      acc[1][nt] = MFMA16(A1H, BL[nt], acc[1][nt]);           \
      acc[1][nt] = MFMA16(A1L, BH[nt], acc[1][nt]);           \
    }

  if constexpr (NKC > 0) {                     // act part (K = NKC*32, NKC even)
    int wr[NT];
#pragma unroll
    for (int nt = 0; nt < NT; ++nt) wr[nt] = (nBase + nt*16 + lm) * kStr + kb0;
    bf16x8 bhA[NT], blA[NT], bhB[NT], blB[NT];
#pragma unroll
    for (int nt = 0; nt < NT; ++nt) {          // preload weights kc=0 -> A
      bhA[nt] = *(const bf16x8*)(wHi + wr[nt]);
      blA[nt] = *(const bf16x8*)(wLo + wr[nt]);
    }
#pragma unroll
    for (int kc = 0; kc < NKC; kc += 2) {
#pragma unroll
      for (int nt = 0; nt < NT; ++nt) {        // prefetch weights kc+1 -> B
        bhB[nt] = *(const bf16x8*)(wHi + wr[nt] + (kc+1)*32);
        blB[nt] = *(const bf16x8*)(wLo + wr[nt] + (kc+1)*32);
      }
      {                                        // act kc, MFMA with A
        const int kb = kc * 32;
        bf16x8 a0h = *(const bf16x8*)(aHi + ar + kb);
        bf16x8 a0l = *(const bf16x8*)(aLo + ar + kb);
        bf16x8 a1h = *(const bf16x8*)(aHi + ar + 16*AH + kb);
        bf16x8 a1l = *(const bf16x8*)(aLo + ar + 16*AH + kb);
        MFMA_BLK(bhA, blA, a0h, a0l, a1h, a1l)
      }
      if (kc + 2 < NKC) {                      // prefetch weights kc+2 -> A
#pragma unroll
        for (int nt = 0; nt < NT; ++nt) {
          bhA[nt] = *(const bf16x8*)(wHi + wr[nt] + (kc+2)*32);
          blA[nt] = *(const bf16x8*)(wLo + wr[nt] + (kc+2)*32);
        }
      }
      {                                        // act kc+1, MFMA with B
        const int kb = (kc+1) * 32;
        bf16x8 a0h = *(const bf16x8*)(aHi + ar + kb);
        bf16x8 a0l = *(const bf16x8*)(aLo + ar + kb);
        bf16x8 a1h = *(const bf16x8*)(aHi + ar + 16*AH + kb);
        bf16x8 a1l = *(const bf16x8*)(aLo + ar + 16*AH + kb);
        MFMA_BLK(bhB, blB, a0h, a0l, a1h, a1l)
      }
    }
  }
  if (xHi) {                                   // px part, K=64 (zero-padded tail)
    bf16x8 bh0[NT], bl0[NT], bh1[NT], bl1[NT];
#pragma unroll
    for (int nt = 0; nt < NT; ++nt) {          // both kc weight sets up front
      const int ro = (nBase + nt*16 + lm)*64 + kb0;
      bh0[nt] = *(const bf16x8*)(xHi + ro);
      bl0[nt] = *(const bf16x8*)(xLo + ro);
      bh1[nt] = *(const bf16x8*)(xHi + ro + 32);
      bl1[nt] = *(const bf16x8*)(xLo + ro + 32);
    }
#pragma unroll
    for (int kc = 0; kc < 2; ++kc) {
      const int kb = kc * 32;
      bf16x8 ah[2], al[2];
#pragma unroll
      for (int mt = 0; mt < 2; ++mt) {
        const f16x8 pv = *(const f16x8*)((const _Float16*)pxh + (mBase + mt*16 + lm)*64 + kb0 + kb);
#pragma unroll
        for (int j = 0; j < 8; ++j) {
          float v = (float)pv[j];
          __bf16 h = (__bf16)v;
          ah[mt][j] = h;
          al[mt][j] = (__bf16)(v - (float)h);
        }
      }
#pragma unroll
      for (int nt = 0; nt < NT; ++nt) {
        acc[0][nt] = MFMA16(ah[0], kc ? bh1[nt] : bh0[nt], acc[0][nt]);
        acc[0][nt] = MFMA16(ah[0], kc ? bl1[nt] : bl0[nt], acc[0][nt]);
        acc[0][nt] = MFMA16(al[0], kc ? bh1[nt] : bh0[nt], acc[0][nt]);
        acc[1][nt] = MFMA16(ah[1], kc ? bh1[nt] : bh0[nt], acc[1][nt]);
        acc[1][nt] = MFMA16(ah[1], kc ? bl1[nt] : bl0[nt], acc[1][nt]);
        acc[1][nt] = MFMA16(al[1], kc ? bh1[nt] : bh0[nt], acc[1][nt]);
      }
    }
  }
#undef MFMA_BLK
  __syncthreads();                 // all reads of act complete
#pragma unroll
  for (int nt = 0; nt < NT; ++nt) {
    const int col = nBase + nt*16 + lm;
    float bv = bias[col] + (pdW ? pdW[col] : 0.f);
#pragma unroll
    for (int mt = 0; mt < 2; ++mt)
#pragma unroll
      for (int r = 0; r < 4; ++r) {
        const int row = mBase + mt*16 + kq*4 + r;
        float v = acc[mt][nt][r] + bv;
        if (relu) v = fmaxf(v, 0.f);
        __bf16 h = (__bf16)v;
        aHi[row*AH + col] = h;
        aLo[row*AH + col] = (__bf16)(v - (float)h);
      }
  }
  __syncthreads();
}

// ======== HALF=0 fallback layer (proven R3 structure) ========
template<int NT, int HALF>
__device__ __forceinline__ void mfma_layer(__bf16* aHi, __bf16* aLo, const __half* pxh,
    const __bf16* __restrict__ wHi, const __bf16* __restrict__ wLo, int kStr, int nkc,
    const __bf16* __restrict__ xHi, const __bf16* __restrict__ xLo,
    const float* __restrict__ bias, const float* __restrict__ pdW,
    bool relu, int tid) {
  const int wave = tid >> 6, lane = tid & 63;
  const int lm = lane & 15, kq = lane >> 4;
  const int mBase = HALF ? 0 : (wave >> 2) * 64;
  const int nBase = (HALF ? wave : (wave & 3)) * (NT * 16);
  f32x4 acc[4][NT];
#pragma unroll
  for (int mt = 0; mt < 4; ++mt)
#pragma unroll
    for (int nt = 0; nt < NT; ++nt)
#pragma unroll
      for (int e = 0; e < 4; ++e) acc[mt][nt][e] = 0.f;

  if (nkc >= 2) {
    for (int kc = 0; kc < nkc; ++kc) {
      const int kb = kc*32 + kq*8;
      bf16x8 ah[4], al[4], bh[NT], bl[NT];
#pragma unroll
      for (int mt = 0; mt < 4; ++mt) {
        const int off = (mBase + mt*16 + lm)*AH + kb;
        ah[mt] = *(const bf16x8*)(aHi + off);
        al[mt] = *(const bf16x8*)(aLo + off);
      }
#pragma unroll
      for (int nt = 0; nt < NT; ++nt) {
        const int ro = (nBase + nt*16 + lm)*kStr + kb;
        bh[nt] = *(const bf16x8*)(wHi + ro);
        bl[nt] = *(const bf16x8*)(wLo + ro);
      }
#pragma unroll
      for (int p = 0; p < 3; ++p)
#pragma unroll
        for (int mt = 0; mt < 4; ++mt)
#pragma unroll
          for (int nt = 0; nt < NT; ++nt)
            acc[mt][nt] = __builtin_amdgcn_mfma_f32_16x16x32_bf16(
                (p == 2) ? al[mt] : ah[mt],
                (p == 1) ? bl[nt] : bh[nt],
                acc[mt][nt], 0, 0, 0);
    }
  }
  if (xHi) {
#pragma unroll
    for (int kc = 0; kc < 2; ++kc) {
      const int kb = kc*32 + kq*8;
      bf16x8 bh[NT], bl[NT];
#pragma unroll
      for (int nt = 0; nt < NT; ++nt) {
        const int ro = (nBase + nt*16 + lm)*64 + kb;
        bh[nt] = *(const bf16x8*)(xHi + ro);
        bl[nt] = *(const bf16x8*)(xLo + ro);
      }
#pragma unroll
      for (int mp = 0; mp < 2; ++mp) {
        bf16x8 ah[2], al[2];
#pragma unroll
        for (int i = 0; i < 2; ++i) {
          const f16x8 pv = *(const f16x8*)((const _Float16*)pxh + (mBase + (2*mp+i)*16 + lm)*64 + kb);
#pragma unroll
          for (int j = 0; j < 8; ++j) {
            float v = (float)pv[j];
            __bf16 h = (__bf16)v;
            ah[i][j] = h;
            al[i][j] = (__bf16)(v - (float)h);
          }
        }
#pragma unroll
        for (int nt = 0; nt < NT; ++nt) {
          acc[2*mp  ][nt] = MFMA16(ah[0], bh[nt], acc[2*mp  ][nt]);
          acc[2*mp+1][nt] = MFMA16(ah[1], bh[nt], acc[2*mp+1][nt]);
          acc[2*mp  ][nt] = MFMA16(ah[0], bl[nt], acc[2*mp  ][nt]);
          acc[2*mp+1][nt] = MFMA16(ah[1], bl[nt], acc[2*mp+1][nt]);
          acc[2*mp  ][nt] = MFMA16(al[0], bh[nt], acc[2*mp  ][nt]);
          acc[2*mp+1][nt] = MFMA16(al[1], bh[nt], acc[2*mp+1][nt]);
        }
      }
    }
  }
  __syncthreads();
#pragma unroll
  for (int mt = 0; mt < 4; ++mt)
#pragma unroll
    for (int nt = 0; nt < NT; ++nt) {
      const int col = nBase + nt*16 + lm;
      float bv = bias[col] + (pdW ? pdW[col] : 0.f);
#pragma unroll
      for (int r = 0; r < 4; ++r) {
        const int row = mBase + mt*16 + kq*4 + r;
        float v = acc[mt][nt][r] + bv;
        if (relu) v = fmaxf(v, 0.f);
        __bf16 h = (__bf16)v;
        aHi[row*AH + col] = h;
        aLo[row*AH + col] = (__bf16)(v - (float)h);
      }
    }
  __syncthreads();
}

// HALF=1: blockIdx = ray*2 + half, covers samples [half*64, half*64+64)
// HALF=0: blockIdx = ray, covers all 128 samples (fallback config)
// waves_per_eu(4,4): pins MAX waves/EU to 4 (what 76KB LDS enforces anyway) so
// the allocator uses the full 128-VGPR budget instead of targeting 64 regs for
// an unreachable 8-wave occupancy (R6: 487 MB scratch spill without this).
template<int HALF>
__global__ __launch_bounds__(512) __attribute__((amdgpu_waves_per_eu(4, 4)))
void nerf_main(
    const float* __restrict__ ro, const float* __restrict__ rd, const float* __restrict__ tin,
    const float* __restrict__ b0, const float* __restrict__ bh,
    const float* __restrict__ b5, const float* __restrict__ b6,
    const float* __restrict__ b7,
    const float* __restrict__ Wsig, const float* __restrict__ bs,
    const float* __restrict__ bfb,
    const float* __restrict__ Wm, const float* __restrict__ bm,
    const float* __restrict__ Wr, const float* __restrict__ br,
    const __bf16* __restrict__ wsHi, const __bf16* __restrict__ wsLo,
    float* __restrict__ part, float* __restrict__ out) {
  constexpr int M = HALF ? 64 : 128;
  __shared__ __align__(16) __bf16 aHi[M * AH];
  __shared__ __align__(16) __bf16 aLo[M * AH];
  __shared__ __align__(16) unsigned char pxred[M * 128];  // pxh (M*64 halves) / red union
  __shared__ __align__(16) float  pdBuf[24];
  __shared__ __align__(16) float  pdW[128];
  __shared__ __align__(16) float  tBuf[M + 4];
  __shared__ __align__(16) float  sigBuf[M];
  __shared__ __align__(16) float  rgbBuf[M * 3];

  __half* pxh = (__half*)pxred;
  float*  red = (float*)pxred;         // used after pxh dead (sigma head onward)

  const int blk  = blockIdx.x;
  const int ray  = HALF ? (blk >> 1) : blk;
  const int S    = HALF ? (blk & 1) * 64 : 0;
  const int tid  = threadIdx.x;

  // ---- positional encodings ----
  if (tid < M) {
    const int m = tid;
    float tv = tin[ray*128 + S + m];
    tBuf[m] = tv;
    float xs[3];
#pragma unroll
    for (int c = 0; c < 3; ++c) xs[c] = ro[ray*3 + c] + tv * rd[ray*3 + c];
#pragma unroll
    for (int i = 0; i < 10; ++i)
#pragma unroll
      for (int c = 0; c < 3; ++c) {
        float a = ldexpf(xs[c], i);                 // sin(2^i*pi*x) = sinpi(2^i*x)
        pxh[m*64 + i*6 + c]     = __float2half(sinpif(a));
        pxh[m*64 + i*6 + 3 + c] = __float2half(cospif(a));
      }
#pragma unroll
    for (int j = 60; j < 64; ++j) pxh[m*64 + j] = __float2half(0.f);
  } else if (tid < M + 24) {
    int j = tid - M;
    int i = j / 6, r = j % 6;
    float a = ldexpf(rd[ray*3 + (r % 3)], i);
    pdBuf[j] = (r < 3) ? sinpif(a) : cospif(a);
  } else if (tid == M + 24) {
    tBuf[M] = (S + M < 128) ? tin[ray*128 + S + M] : 0.f;   // next-t for last delta
  }
  __syncthreads();
  if (tid >= 256 && tid < 384) {       // pdW[c] = sum_j pd[j]*Wm[256+j][c]
    int c = tid - 256;
    float s = 0.f;
#pragma unroll
    for (int j = 0; j < 24; ++j) s += pdBuf[j] * Wm[(256 + j)*128 + c];
    pdW[c] = s;
  }
  __syncthreads();

  // ---- trunk ----
  if constexpr (HALF) {
    layer_row<4, 0>(aHi, aLo, pxh, nullptr, nullptr, 0,
                    wsHi + OFF_W0T, wsLo + OFF_W0T, b0, nullptr, true, tid);
    for (int i = 0; i < 4; ++i)
      layer_row<4, 8>(aHi, aLo, pxh, wsHi + OFF_WHT + i*65536, wsLo + OFF_WHT + i*65536, 256,
                      nullptr, nullptr, bh + i*256, nullptr, true, tid);
    layer_row<4, 8>(aHi, aLo, pxh, wsHi + OFF_W5AT, wsLo + OFF_W5AT, 256,
                    wsHi + OFF_W5BT, wsLo + OFF_W5BT, b5, nullptr, true, tid);
    layer_row<4, 8>(aHi, aLo, pxh, wsHi + OFF_W6T, wsLo + OFF_W6T, 256,
                    nullptr, nullptr, b6, nullptr, true, tid);
    layer_row<4, 8>(aHi, aLo, pxh, wsHi + OFF_W7T, wsLo + OFF_W7T, 256,
                    nullptr, nullptr, b7, nullptr, true, tid);
  } else {
    mfma_layer<4, 0>(aHi, aLo, pxh, nullptr, nullptr, 0, 0,
                     wsHi + OFF_W0T, wsLo + OFF_W0T, b0, nullptr, true, tid);
    for (int i = 0; i < 4; ++i)
      mfma_layer<4, 0>(aHi, aLo, pxh, wsHi + OFF_WHT + i*65536, wsLo + OFF_WHT + i*65536, 256, 8,
                       nullptr, nullptr, bh + i*256, nullptr, true, tid);
    mfma_layer<4, 0>(aHi, aLo, pxh, wsHi + OFF_W5AT, wsLo + OFF_W5AT, 256, 8,
                     wsHi + OFF_W5BT, wsLo + OFF_W5BT, b5, nullptr, true, tid);
    mfma_layer<4, 0>(aHi, aLo, pxh, wsHi + OFF_W6T, wsLo + OFF_W6T, 256, 8,
                     nullptr, nullptr, b6, nullptr, true, tid);
    mfma_layer<4, 0>(aHi, aLo, pxh, wsHi + OFF_W7T, wsLo + OFF_W7T, 256, 8,
                     nullptr, nullptr, b7, nullptr, true, tid);
  }

  // sigma = relu(h @ Ws + bs)   (pxh now dead -> red)
  {
    constexpr int TPS = 512 / M;       // threads per sample (8 or 4)
    const int m = tid / TPS, q = tid % TPS;
    const int kn = 256 / TPS;
    float s = 0.f;
    for (int k8 = q*kn; k8 < q*kn + kn; k8 += 8) {
      bf16x8 vh = *(const bf16x8*)(aHi + m*AH + k8);
      bf16x8 vl = *(const bf16x8*)(aLo + m*AH + k8);
#pragma unroll
      for (int j = 0; j < 8; ++j) s += ((float)vh[j] + (float)vl[j]) * Wsig[k8 + j];
    }
    red[tid] = s;
    __syncthreads();
    if (tid < M) {
      float sm = bs[0];
#pragma unroll
      for (int j = 0; j < TPS; ++j) sm += red[TPS*tid + j];
      sigBuf[tid] = fmaxf(sm, 0.f);
    }
    __syncthreads();
  }

  // feat = h @ Wf + bf (no relu)
  if constexpr (HALF)
    layer_row<4, 8>(aHi, aLo, nullptr, wsHi + OFF_WFT, wsLo + OFF_WFT, 256,
                    nullptr, nullptr, bfb, nullptr, false, tid);
  else
    mfma_layer<4, 0>(aHi, aLo, nullptr, wsHi + OFF_WFT, wsLo + OFF_WFT, 256, 8,
                     nullptr, nullptr, bfb, nullptr, false, tid);

  // h2 = relu([feat, pd] @ Wm + bm), N=128 (pd folded via pdW)
  if constexpr (HALF)
    layer_row<2, 8>(aHi, aLo, nullptr, wsHi + OFF_WMAT, wsLo + OFF_WMAT, 256,
                    nullptr, nullptr, bm, pdW, true, tid);
  else
    mfma_layer<2, 0>(aHi, aLo, nullptr, wsHi + OFF_WMAT, wsLo + OFF_WMAT, 256, 8,
                     nullptr, nullptr, bm, pdW, true, tid);

  // rgb = sigmoid(h2 @ Wr + br)
  {
    constexpr int TPS = 512 / M;
    const int m = tid / TPS, q = tid % TPS;
    const int kn = 128 / TPS;
    float r0s = 0.f, r1s = 0.f, r2s = 0.f;
    for (int k8 = q*kn; k8 < q*kn + kn; k8 += 8) {
      bf16x8 vh = *(const bf16x8*)(aHi + m*AH + k8);
      bf16x8 vl = *(const bf16x8*)(aLo + m*AH + k8);
#pragma unroll
      for (int j = 0; j < 8; ++j) {
        float hv = (float)vh[j] + (float)vl[j];
        r0s += hv * Wr[(k8 + j)*3 + 0];
        r1s += hv * Wr[(k8 + j)*3 + 1];
        r2s += hv * Wr[(k8 + j)*3 + 2];
      }
    }
    red[tid] = r0s; red[512 + tid] = r1s; red[1024 + tid] = r2s;
    __syncthreads();
    if (tid < M) {
#pragma unroll
      for (int c = 0; c < 3; ++c) {
        float sm = br[c];
#pragma unroll
        for (int j = 0; j < TPS; ++j) sm += red[c*512 + TPS*tid + j];
        rgbBuf[tid*3 + c] = 1.f / (1.f + expf(-sm));
      }
    }
    __syncthreads();
  }

  // volume rendering: serial transmittance scan over this block's segment
  if (tid == 0) {
    float T = 1.f, c0 = 0.f, c1 = 0.f, c2 = 0.f, wsum = 0.f;
    for (int m = 0; m < M; ++m) {
      float delta = (S + m < 127) ? (tBuf[m + 1] - tBuf[m]) : 1e8f;
      float e = expf(-sigBuf[m] * delta);
      float w = T * (1.f - e);
      c0 += w * rgbBuf[m*3 + 0];
      c1 += w * rgbBuf[m*3 + 1];
      c2 += w * rgbBuf[m*3 + 2];
      wsum += w;
      T *= e;
    }
    if (HALF) {
      float* p = part + blk*5;
      p[0] = c0; p[1] = c1; p[2] = c2; p[3] = wsum; p[4] = T;
    } else {
      float bg = 1.f - wsum;           // C_BG = (1,1,1)
      out[ray*3 + 0] = c0 + bg;
      out[ray*3 + 1] = c1 + bg;
      out[ray*3 + 2] = c2 + bg;
    }
  }
}

__global__ void combine(const float* __restrict__ part, float* __restrict__ out) {
  int r = blockIdx.x * blockDim.x + threadIdx.x;
  if (r >= 2048) return;
  const float* p0 = part + (2*r)*5;
  const float* p1 = p0 + 5;
  float T0 = p0[4];
  float wsum = p0[3] + T0 * p1[3];
  float bg = 1.f - wsum;               // C_BG = (1,1,1)
#pragma unroll
  for (int c = 0; c < 3; ++c)
    out[r*3 + c] = p0[c] + T0 * p1[c] + bg;
}

extern "C" void kernel_launch(void* const* d_in, const int* in_sizes, int n_in,
                              void* d_out, int out_size, void* d_ws, size_t ws_size,
                              hipStream_t stream) {
  const float* ro  = (const float*)d_in[0];
  const float* rd  = (const float*)d_in[1];
  const float* t   = (const float*)d_in[2];
  const float* W0  = (const float*)d_in[3];
  const float* b0  = (const float*)d_in[4];
  const float* Wh  = (const float*)d_in[5];
  const float* bh  = (const float*)d_in[6];
  const float* W5  = (const float*)d_in[7];
  const float* b5  = (const float*)d_in[8];
  const float* W6  = (const float*)d_in[9];
  const float* b6  = (const float*)d_in[10];
  const float* W7  = (const float*)d_in[11];
  const float* b7  = (const float*)d_in[12];
  const float* Wsg = (const float*)d_in[13];
  const float* bs  = (const float*)d_in[14];
  const float* Wf  = (const float*)d_in[15];
  const float* bfb = (const float*)d_in[16];
  const float* Wm  = (const float*)d_in[17];
  const float* bm  = (const float*)d_in[18];
  const float* Wr  = (const float*)d_in[19];
  const float* br  = (const float*)d_in[20];
  float* out = (float*)d_out;

  __bf16* wsHi = (__bf16*)d_ws;                     // 2*TOT bf16 = 2.36 MB (proven)
  __bf16* wsLo = wsHi + TOT;
  float*  part = (float*)((char*)d_ws + (size_t)2 * TOT * 2);   // 4096*5 floats = 80 KB

  const size_t needSplit = (size_t)2 * TOT * 2 + (size_t)4096 * 5 * 4;

  prep_weights<<<(TOT + 255)/256, 256, 0, stream>>>(W0, Wh, W5, W6, W7, Wf, Wm, wsHi);
  if (ws_size >= needSplit) {
    nerf_main<1><<<4096, 512, 0, stream>>>(ro, rd, t, b0, bh, b5, b6, b7,
                                           Wsg, bs, bfb, Wm, bm, Wr, br,
                                           wsHi, wsLo, part, out);
    combine<<<8, 256, 0, stream>>>(part, out);
  } else {
    nerf_main<0><<<2048, 512, 0, stream>>>(ro, rd, t, b0, bh, b5, b6, b7,
                                           Wsg, bs, bfb, Wm, bm, Wr, br,
                                           wsHi, wsLo, part, out);
  }
}

// Round 8
// 2230.852 us; speedup vs baseline: 1.0614x; 1.0614x over previous
//
#include <hip/hip_runtime.h>
#include <hip/hip_fp16.h>
#include <math.h>

typedef __bf16   bf16x8 __attribute__((ext_vector_type(8)));
typedef _Float16 f16x8  __attribute__((ext_vector_type(8)));
typedef float    f32x4  __attribute__((ext_vector_type(4)));

#define AH  264              // act plane stride (bf16)
#define TOT 589824           // staged weight elems (hi); lo at +TOT

// staged ws layout (bf16, [n][k] transposed, zero-padded K tails)
#define OFF_W0T   0          // [256][64]
#define OFF_WHT   16384      // 4 x [256][256]
#define OFF_W5AT  278528     // [256][256]
#define OFF_W5BT  344064     // [256][64]
#define OFF_W6T   360448     // [256][256]
#define OFF_W7T   425984     // [256][256]
#define OFF_WFT   491520     // [256][256]
#define OFF_WMAT  557056     // [128][256]

__global__ void prep_weights(const float* __restrict__ W0, const float* __restrict__ Wh,
                             const float* __restrict__ W5, const float* __restrict__ W6,
                             const float* __restrict__ W7, const float* __restrict__ Wf,
                             const float* __restrict__ Wm, __bf16* __restrict__ ws) {
  int idx = blockIdx.x * blockDim.x + threadIdx.x;
  if (idx >= TOT) return;
  float v = 0.f;
  if (idx < OFF_WHT)        { int j = idx;            int n=j>>6, k=j&63;   v = (k<60)? W0[k*256+n] : 0.f; }
  else if (idx < OFF_W5AT)  { int j = idx - OFF_WHT;  int i=j>>16, r=j&65535, n=r>>8, k=r&255; v = Wh[i*65536+k*256+n]; }
  else if (idx < OFF_W5BT)  { int j = idx - OFF_W5AT; int n=j>>8, k=j&255;  v = W5[k*256+n]; }
  else if (idx < OFF_W6T)   { int j = idx - OFF_W5BT; int n=j>>6, k=j&63;   v = (k<60)? W5[(256+k)*256+n] : 0.f; }
  else if (idx < OFF_W7T)   { int j = idx - OFF_W6T;  int n=j>>8, k=j&255;  v = W6[k*256+n]; }
  else if (idx < OFF_WFT)   { int j = idx - OFF_W7T;  int n=j>>8, k=j&255;  v = W7[k*256+n]; }
  else if (idx < OFF_WMAT)  { int j = idx - OFF_WFT;  int n=j>>8, k=j&255;  v = Wf[k*256+n]; }
  else                      { int j = idx - OFF_WMAT; int n=j>>8, k=j&255;  v = Wm[k*128+n]; }
  __bf16 hi = (__bf16)v;
  ws[idx] = hi;
  ws[TOT + idx] = (__bf16)(v - (float)hi);
}

#define MFMA16(A,B,C) __builtin_amdgcn_mfma_f32_16x16x32_bf16((A),(B),(C),0,0,0)

// ======== HALF=1 layer: 2m x 4n wave decomposition (M=64) ========
// wave = (mi=wave>>2)*32 rows x (ni=wave&3)*(NT*16) cols. Each wave reads only
// its 32 A-rows from LDS (halves act traffic + bank conflicts vs all-M x 1/8N:
// measured 8.6e7 -> 4.5e7 twice). SINGLE weight buffer + fully-unrolled NKC:
// live set ~95 regs (acc 32 AGPR + wfrag 32 + act 16 + addr) fits the HARD
// 128-reg/wave budget at 4 waves/SIMD (2 blocks x 76KB LDS), leaving ~30 regs
// for the compiler to hoist next-kc loads across unrolled iterations.
// (R6/R7 post-mortem: explicit NT=4 A/B dbuf needs ~140 regs -> 487 MB scratch
// spill, infeasible at this occupancy in ANY form. R5: runtime-nkc loop -> no
// unroll -> zero overlap, 2302us. This is the feasible middle.)
// Per-element accumulation order: kc ascending; a_h*b_h, a_h*b_l, a_l*b_h
// -> bit-identical to all prior versions.
template<int NT, int NKC>
__device__ __forceinline__ void layer_row(__bf16* aHi, __bf16* aLo, const __half* pxh,
    const __bf16* __restrict__ wHi, const __bf16* __restrict__ wLo, int kStr,
    const __bf16* __restrict__ xHi, const __bf16* __restrict__ xLo,  // px weights or null
    const float* __restrict__ bias, const float* __restrict__ pdW,
    bool relu, int tid) {
  const int wave = tid >> 6, lane = tid & 63;
  const int lm = lane & 15, kq = lane >> 4;
  const int mBase = (wave >> 2) * 32;          // mi in {0,1}
  const int nBase = (wave & 3) * (NT * 16);    // ni in {0..3}
  f32x4 acc[2][NT];
#pragma unroll
  for (int mt = 0; mt < 2; ++mt)
#pragma unroll
    for (int nt = 0; nt < NT; ++nt)
#pragma unroll
      for (int e = 0; e < 4; ++e) acc[mt][nt][e] = 0.f;

  const int kb0 = kq * 8;
  const int ar = (mBase + lm) * AH + kb0;

#define MFMA_BLK(BH,BL,A0H,A0L,A1H,A1L)                       \
    _Pragma("unroll")                                         \
    for (int nt = 0; nt < NT; ++nt) {                         \
      acc[0][nt] = MFMA16(A0H, BH[nt], acc[0][nt]);           \
      acc[0][nt] = MFMA16(A0H, BL[nt], acc[0][nt]);           \
      acc[0][nt] = MFMA16(A0L, BH[nt], acc[0][nt]);           \
      acc[1][nt] = MFMA16(A1H, BH[nt], acc[1][nt]);           \
      acc[1][nt] = MFMA16(A1H, BL[nt], acc[1][nt]);           \
      acc[1][nt] = MFMA16(A1L, BH[nt], acc[1][nt]);           \
    }

  if constexpr (NKC > 0) {                     // act part (K = NKC*32)
    int wr[NT];
#pragma unroll
    for (int nt = 0; nt < NT; ++nt) wr[nt] = (nBase + nt*16 + lm) * kStr + kb0;
#pragma unroll
    for (int kc = 0; kc < NKC; ++kc) {
      const int kb = kc * 32;
      bf16x8 bh[NT], bl[NT];
#pragma unroll
      for (int nt = 0; nt < NT; ++nt) {        // single-buffer weight loads;
        bh[nt] = *(const bf16x8*)(wHi + wr[nt] + kb);   // unrolled loop lets the
        bl[nt] = *(const bf16x8*)(wLo + wr[nt] + kb);   // scheduler hoist ahead
      }
      bf16x8 a0h = *(const bf16x8*)(aHi + ar + kb);
      bf16x8 a0l = *(const bf16x8*)(aLo + ar + kb);
      bf16x8 a1h = *(const bf16x8*)(aHi + ar + 16*AH + kb);
      bf16x8 a1l = *(const bf16x8*)(aLo + ar + 16*AH + kb);
      MFMA_BLK(bh, bl, a0h, a0l, a1h, a1l)
    }
  }
  if (xHi) {                                   // px part, K=64 (zero-padded tail)
#pragma unroll
    for (int kc = 0; kc < 2; ++kc) {
      const int kb = kc * 32;
      bf16x8 bh[NT], bl[NT];
#pragma unroll
      for (int nt = 0; nt < NT; ++nt) {
        const int ro = (nBase + nt*16 + lm)*64 + kb0 + kb;
        bh[nt] = *(const bf16x8*)(xHi + ro);
        bl[nt] = *(const bf16x8*)(xLo + ro);
      }
      bf16x8 ah[2], al[2];
#pragma unroll
      for (int mt = 0; mt < 2; ++mt) {
        const f16x8 pv = *(const f16x8*)((const _Float16*)pxh + (mBase + mt*16 + lm)*64 + kb0 + kb);
#pragma unroll
        for (int j = 0; j < 8; ++j) {
          float v = (float)pv[j];
          __bf16 h = (__bf16)v;
          ah[mt][j] = h;
          al[mt][j] = (__bf16)(v - (float)h);
        }
      }
      MFMA_BLK(bh, bl, ah[0], al[0], ah[1], al[1])
    }
  }
#undef MFMA_BLK
  __syncthreads();                 // all reads of act complete
#pragma unroll
  for (int nt = 0; nt < NT; ++nt) {
    const int col = nBase + nt*16 + lm;
    float bv = bias[col] + (pdW ? pdW[col] : 0.f);
#pragma unroll
    for (int mt = 0; mt < 2; ++mt)
#pragma unroll
      for (int r = 0; r < 4; ++r) {
        const int row = mBase + mt*16 + kq*4 + r;
        float v = acc[mt][nt][r] + bv;
        if (relu) v = fmaxf(v, 0.f);
        __bf16 h = (__bf16)v;
        aHi[row*AH + col] = h;
        aLo[row*AH + col] = (__bf16)(v - (float)h);
      }
  }
  __syncthreads();
}

// ======== HALF=0 fallback layer (R3 structure, runtime nkc) ========
template<int NT, int HALF>
__device__ __forceinline__ void mfma_layer(__bf16* aHi, __bf16* aLo, const __half* pxh,
    const __bf16* __restrict__ wHi, const __bf16* __restrict__ wLo, int kStr, int nkc,
    const __bf16* __restrict__ xHi, const __bf16* __restrict__ xLo,
    const float* __restrict__ bias, const float* __restrict__ pdW,
    bool relu, int tid) {
  const int wave = tid >> 6, lane = tid & 63;
  const int lm = lane & 15, kq = lane >> 4;
  const int mBase = HALF ? 0 : (wave >> 2) * 64;
  const int nBase = (HALF ? wave : (wave & 3)) * (NT * 16);
  f32x4 acc[4][NT];
#pragma unroll
  for (int mt = 0; mt < 4; ++mt)
#pragma unroll
    for (int nt = 0; nt < NT; ++nt)
#pragma unroll
      for (int e = 0; e < 4; ++e) acc[mt][nt][e] = 0.f;

  if (nkc >= 2) {
    for (int kc = 0; kc < nkc; ++kc) {
      const int kb = kc*32 + kq*8;
      bf16x8 ah[4], al[4], bh[NT], bl[NT];
#pragma unroll
      for (int mt = 0; mt < 4; ++mt) {
        const int off = (mBase + mt*16 + lm)*AH + kb;
        ah[mt] = *(const bf16x8*)(aHi + off);
        al[mt] = *(const bf16x8*)(aLo + off);
      }
#pragma unroll
      for (int nt = 0; nt < NT; ++nt) {
        const int ro = (nBase + nt*16 + lm)*kStr + kb;
        bh[nt] = *(const bf16x8*)(wHi + ro);
        bl[nt] = *(const bf16x8*)(wLo + ro);
      }
#pragma unroll
      for (int p = 0; p < 3; ++p)
#pragma unroll
        for (int mt = 0; mt < 4; ++mt)
#pragma unroll
          for (int nt = 0; nt < NT; ++nt)
            acc[mt][nt] = __builtin_amdgcn_mfma_f32_16x16x32_bf16(
                (p == 2) ? al[mt] : ah[mt],
                (p == 1) ? bl[nt] : bh[nt],
                acc[mt][nt], 0, 0, 0);
    }
  }
  if (xHi) {
#pragma unroll
    for (int kc = 0; kc < 2; ++kc) {
      const int kb = kc*32 + kq*8;
      bf16x8 bh[NT], bl[NT];
#pragma unroll
      for (int nt = 0; nt < NT; ++nt) {
        const int ro = (nBase + nt*16 + lm)*64 + kb;
        bh[nt] = *(const bf16x8*)(xHi + ro);
        bl[nt] = *(const bf16x8*)(xLo + ro);
      }
#pragma unroll
      for (int mp = 0; mp < 2; ++mp) {
        bf16x8 ah[2], al[2];
#pragma unroll
        for (int i = 0; i < 2; ++i) {
          const f16x8 pv = *(const f16x8*)((const _Float16*)pxh + (mBase + (2*mp+i)*16 + lm)*64 + kb);
#pragma unroll
          for (int j = 0; j < 8; ++j) {
            float v = (float)pv[j];
            __bf16 h = (__bf16)v;
            ah[i][j] = h;
            al[i][j] = (__bf16)(v - (float)h);
          }
        }
#pragma unroll
        for (int nt = 0; nt < NT; ++nt) {
          acc[2*mp  ][nt] = MFMA16(ah[0], bh[nt], acc[2*mp  ][nt]);
          acc[2*mp+1][nt] = MFMA16(ah[1], bh[nt], acc[2*mp+1][nt]);
          acc[2*mp  ][nt] = MFMA16(ah[0], bl[nt], acc[2*mp  ][nt]);
          acc[2*mp+1][nt] = MFMA16(ah[1], bl[nt], acc[2*mp+1][nt]);
          acc[2*mp  ][nt] = MFMA16(al[0], bh[nt], acc[2*mp  ][nt]);
          acc[2*mp+1][nt] = MFMA16(al[1], bh[nt], acc[2*mp+1][nt]);
        }
      }
    }
  }
  __syncthreads();
#pragma unroll
  for (int mt = 0; mt < 4; ++mt)
#pragma unroll
    for (int nt = 0; nt < NT; ++nt) {
      const int col = nBase + nt*16 + lm;
      float bv = bias[col] + (pdW ? pdW[col] : 0.f);
#pragma unroll
      for (int r = 0; r < 4; ++r) {
        const int row = mBase + mt*16 + kq*4 + r;
        float v = acc[mt][nt][r] + bv;
        if (relu) v = fmaxf(v, 0.f);
        __bf16 h = (__bf16)v;
        aHi[row*AH + col] = h;
        aLo[row*AH + col] = (__bf16)(v - (float)h);
      }
    }
  __syncthreads();
}

// HALF=1: blockIdx = ray*2 + half, covers samples [half*64, half*64+64)
// HALF=0: blockIdx = ray, covers all 128 samples (fallback config)
template<int HALF>
__global__ __launch_bounds__(512, 4)
void nerf_main(
    const float* __restrict__ ro, const float* __restrict__ rd, const float* __restrict__ tin,
    const float* __restrict__ b0, const float* __restrict__ bh,
    const float* __restrict__ b5, const float* __restrict__ b6,
    const float* __restrict__ b7,
    const float* __restrict__ Wsig, const float* __restrict__ bs,
    const float* __restrict__ bfb,
    const float* __restrict__ Wm, const float* __restrict__ bm,
    const float* __restrict__ Wr, const float* __restrict__ br,
    const __bf16* __restrict__ wsHi, const __bf16* __restrict__ wsLo,
    float* __restrict__ part, float* __restrict__ out) {
  constexpr int M = HALF ? 64 : 128;
  __shared__ __align__(16) __bf16 aHi[M * AH];
  __shared__ __align__(16) __bf16 aLo[M * AH];
  __shared__ __align__(16) unsigned char pxred[M * 128];  // pxh (M*64 halves) / red union
  __shared__ __align__(16) float  pdBuf[24];
  __shared__ __align__(16) float  pdW[128];
  __shared__ __align__(16) float  tBuf[M + 4];
  __shared__ __align__(16) float  sigBuf[M];
  __shared__ __align__(16) float  rgbBuf[M * 3];

  __half* pxh = (__half*)pxred;
  float*  red = (float*)pxred;         // used after pxh dead (sigma head onward)

  const int blk  = blockIdx.x;
  const int ray  = HALF ? (blk >> 1) : blk;
  const int S    = HALF ? (blk & 1) * 64 : 0;
  const int tid  = threadIdx.x;

  // ---- positional encodings ----
  if (tid < M) {
    const int m = tid;
    float tv = tin[ray*128 + S + m];
    tBuf[m] = tv;
    float xs[3];
#pragma unroll
    for (int c = 0; c < 3; ++c) xs[c] = ro[ray*3 + c] + tv * rd[ray*3 + c];
#pragma unroll
    for (int i = 0; i < 10; ++i)
#pragma unroll
      for (int c = 0; c < 3; ++c) {
        float a = ldexpf(xs[c], i);                 // sin(2^i*pi*x) = sinpi(2^i*x)
        pxh[m*64 + i*6 + c]     = __float2half(sinpif(a));
        pxh[m*64 + i*6 + 3 + c] = __float2half(cospif(a));
      }
#pragma unroll
    for (int j = 60; j < 64; ++j) pxh[m*64 + j] = __float2half(0.f);
  } else if (tid < M + 24) {
    int j = tid - M;
    int i = j / 6, r = j % 6;
    float a = ldexpf(rd[ray*3 + (r % 3)], i);
    pdBuf[j] = (r < 3) ? sinpif(a) : cospif(a);
  } else if (tid == M + 24) {
    tBuf[M] = (S + M < 128) ? tin[ray*128 + S + M] : 0.f;   // next-t for last delta
  }
  __syncthreads();
  if (tid >= 256 && tid < 384) {       // pdW[c] = sum_j pd[j]*Wm[256+j][c]
    int c = tid - 256;
    float s = 0.f;
#pragma unroll
    for (int j = 0; j < 24; ++j) s += pdBuf[j] * Wm[(256 + j)*128 + c];
    pdW[c] = s;
  }
  __syncthreads();

  // ---- trunk ----
  if constexpr (HALF) {
    layer_row<4, 0>(aHi, aLo, pxh, nullptr, nullptr, 0,
                    wsHi + OFF_W0T, wsLo + OFF_W0T, b0, nullptr, true, tid);
    for (int i = 0; i < 4; ++i)
      layer_row<4, 8>(aHi, aLo, pxh, wsHi + OFF_WHT + i*65536, wsLo + OFF_WHT + i*65536, 256,
                      nullptr, nullptr, bh + i*256, nullptr, true, tid);
    layer_row<4, 8>(aHi, aLo, pxh, wsHi + OFF_W5AT, wsLo + OFF_W5AT, 256,
                    wsHi + OFF_W5BT, wsLo + OFF_W5BT, b5, nullptr, true, tid);
    layer_row<4, 8>(aHi, aLo, pxh, wsHi + OFF_W6T, wsLo + OFF_W6T, 256,
                    nullptr, nullptr, b6, nullptr, true, tid);
    layer_row<4, 8>(aHi, aLo, pxh, wsHi + OFF_W7T, wsLo + OFF_W7T, 256,
                    nullptr, nullptr, b7, nullptr, true, tid);
  } else {
    mfma_layer<4, 0>(aHi, aLo, pxh, nullptr, nullptr, 0, 0,
                     wsHi + OFF_W0T, wsLo + OFF_W0T, b0, nullptr, true, tid);
    for (int i = 0; i < 4; ++i)
      mfma_layer<4, 0>(aHi, aLo, pxh, wsHi + OFF_WHT + i*65536, wsLo + OFF_WHT + i*65536, 256, 8,
                       nullptr, nullptr, bh + i*256, nullptr, true, tid);
    mfma_layer<4, 0>(aHi, aLo, pxh, wsHi + OFF_W5AT, wsLo + OFF_W5AT, 256, 8,
                     wsHi + OFF_W5BT, wsLo + OFF_W5BT, b5, nullptr, true, tid);
    mfma_layer<4, 0>(aHi, aLo, pxh, wsHi + OFF_W6T, wsLo + OFF_W6T, 256, 8,
                     nullptr, nullptr, b6, nullptr, true, tid);
    mfma_layer<4, 0>(aHi, aLo, pxh, wsHi + OFF_W7T, wsLo + OFF_W7T, 256, 8,
                     nullptr, nullptr, b7, nullptr, true, tid);
  }

  // sigma = relu(h @ Ws + bs)   (pxh now dead -> red)
  {
    constexpr int TPS = 512 / M;       // threads per sample (8 or 4)
    const int m = tid / TPS, q = tid % TPS;
    const int kn = 256 / TPS;
    float s = 0.f;
    for (int k8 = q*kn; k8 < q*kn + kn; k8 += 8) {
      bf16x8 vh = *(const bf16x8*)(aHi + m*AH + k8);
      bf16x8 vl = *(const bf16x8*)(aLo + m*AH + k8);
#pragma unroll
      for (int j = 0; j < 8; ++j) s += ((float)vh[j] + (float)vl[j]) * Wsig[k8 + j];
    }
    red[tid] = s;
    __syncthreads();
    if (tid < M) {
      float sm = bs[0];
#pragma unroll
      for (int j = 0; j < TPS; ++j) sm += red[TPS*tid + j];
      sigBuf[tid] = fmaxf(sm, 0.f);
    }
    __syncthreads();
  }

  // feat = h @ Wf + bf (no relu)
  if constexpr (HALF)
    layer_row<4, 8>(aHi, aLo, nullptr, wsHi + OFF_WFT, wsLo + OFF_WFT, 256,
                    nullptr, nullptr, bfb, nullptr, false, tid);
  else
    mfma_layer<4, 0>(aHi, aLo, nullptr, wsHi + OFF_WFT, wsLo + OFF_WFT, 256, 8,
                     nullptr, nullptr, bfb, nullptr, false, tid);

  // h2 = relu([feat, pd] @ Wm + bm), N=128 (pd folded via pdW)
  if constexpr (HALF)
    layer_row<2, 8>(aHi, aLo, nullptr, wsHi + OFF_WMAT, wsLo + OFF_WMAT, 256,
                    nullptr, nullptr, bm, pdW, true, tid);
  else
    mfma_layer<2, 0>(aHi, aLo, nullptr, wsHi + OFF_WMAT, wsLo + OFF_WMAT, 256, 8,
                     nullptr, nullptr, bm, pdW, true, tid);

  // rgb = sigmoid(h2 @ Wr + br)
  {
    constexpr int TPS = 512 / M;
    const int m = tid / TPS, q = tid % TPS;
    const int kn = 128 / TPS;
    float r0s = 0.f, r1s = 0.f, r2s = 0.f;
    for (int k8 = q*kn; k8 < q*kn + kn; k8 += 8) {
      bf16x8 vh = *(const bf16x8*)(aHi + m*AH + k8);
      bf16x8 vl = *(const bf16x8*)(aLo + m*AH + k8);
#pragma unroll
      for (int j = 0; j < 8; ++j) {
        float hv = (float)vh[j] + (float)vl[j];
        r0s += hv * Wr[(k8 + j)*3 + 0];
        r1s += hv * Wr[(k8 + j)*3 + 1];
        r2s += hv * Wr[(k8 + j)*3 + 2];
      }
    }
    red[tid] = r0s; red[512 + tid] = r1s; red[1024 + tid] = r2s;
    __syncthreads();
    if (tid < M) {
#pragma unroll
      for (int c = 0; c < 3; ++c) {
        float sm = br[c];
#pragma unroll
        for (int j = 0; j < TPS; ++j) sm += red[c*512 + TPS*tid + j];
        rgbBuf[tid*3 + c] = 1.f / (1.f + expf(-sm));
      }
    }
    __syncthreads();
  }

  // volume rendering: serial transmittance scan over this block's segment
  if (tid == 0) {
    float T = 1.f, c0 = 0.f, c1 = 0.f, c2 = 0.f, wsum = 0.f;
    for (int m = 0; m < M; ++m) {
      float delta = (S + m < 127) ? (tBuf[m + 1] - tBuf[m]) : 1e8f;
      float e = expf(-sigBuf[m] * delta);
      float w = T * (1.f - e);
      c0 += w * rgbBuf[m*3 + 0];
      c1 += w * rgbBuf[m*3 + 1];
      c2 += w * rgbBuf[m*3 + 2];
      wsum += w;
      T *= e;
    }
    if (HALF) {
      float* p = part + blk*5;
      p[0] = c0; p[1] = c1; p[2] = c2; p[3] = wsum; p[4] = T;
    } else {
      float bg = 1.f - wsum;           // C_BG = (1,1,1)
      out[ray*3 + 0] = c0 + bg;
      out[ray*3 + 1] = c1 + bg;
      out[ray*3 + 2] = c2 + bg;
    }
  }
}

__global__ void combine(const float* __restrict__ part, float* __restrict__ out) {
  int r = blockIdx.x * blockDim.x + threadIdx.x;
  if (r >= 2048) return;
  const float* p0 = part + (2*r)*5;
  const float* p1 = p0 + 5;
  float T0 = p0[4];
  float wsum = p0[3] + T0 * p1[3];
  float bg = 1.f - wsum;               // C_BG = (1,1,1)
#pragma unroll
  for (int c = 0; c < 3; ++c)
    out[r*3 + c] = p0[c] + T0 * p1[c] + bg;
}

extern "C" void kernel_launch(void* const* d_in, const int* in_sizes, int n_in,
                              void* d_out, int out_size, void* d_ws, size_t ws_size,
                              hipStream_t stream) {
  const float* ro  = (const float*)d_in[0];
  const float* rd  = (const float*)d_in[1];
  const float* t   = (const float*)d_in[2];
  const float* W0  = (const float*)d_in[3];
  const float* b0  = (const float*)d_in[4];
  const float* Wh  = (const float*)d_in[5];
  const float* bh  = (const float*)d_in[6];
  const float* W5  = (const float*)d_in[7];
  const float* b5  = (const float*)d_in[8];
  const float* W6  = (const float*)d_in[9];
  const float* b6  = (const float*)d_in[10];
  const float* W7  = (const float*)d_in[11];
  const float* b7  = (const float*)d_in[12];
  const float* Wsg = (const float*)d_in[13];
  const float* bs  = (const float*)d_in[14];
  const float* Wf  = (const float*)d_in[15];
  const float* bfb = (const float*)d_in[16];
  const float* Wm  = (const float*)d_in[17];
  const float* bm  = (const float*)d_in[18];
  const float* Wr  = (const float*)d_in[19];
  const float* br  = (const float*)d_in[20];
  float* out = (float*)d_out;

  __bf16* wsHi = (__bf16*)d_ws;                     // 2*TOT bf16 = 2.36 MB (proven)
  __bf16* wsLo = wsHi + TOT;
  float*  part = (float*)((char*)d_ws + (size_t)2 * TOT * 2);   // 4096*5 floats = 80 KB

  const size_t needSplit = (size_t)2 * TOT * 2 + (size_t)4096 * 5 * 4;

  prep_weights<<<(TOT + 255)/256, 256, 0, stream>>>(W0, Wh, W5, W6, W7, Wf, Wm, wsHi);
  if (ws_size >= needSplit) {
    nerf_main<1><<<4096, 512, 0, stream>>>(ro, rd, t, b0, bh, b5, b6, b7,
                                           Wsg, bs, bfb, Wm, bm, Wr, br,
                                           wsHi, wsLo, part, out);
    combine<<<8, 256, 0, stream>>>(part, out);
  } else {
    nerf_main<0><<<2048, 512, 0, stream>>>(ro, rd, t, b0, bh, b5, b6, b7,
                                           Wsg, bs, bfb, Wm, bm, Wr, br,
                                           wsHi, wsLo, part, out);
  }
}

// Round 9
// 2173.818 us; speedup vs baseline: 1.0892x; 1.0262x over previous
//
#include <hip/hip_runtime.h>
#include <hip/hip_fp16.h>
#include <math.h>

typedef __bf16   bf16x8 __attribute__((ext_vector_type(8)));
typedef _Float16 f16x8  __attribute__((ext_vector_type(8)));
typedef float    f32x4  __attribute__((ext_vector_type(4)));

#define AH  264              // act plane stride (bf16)
#define TOT 589824           // staged weight elems (hi); lo at +TOT

// staged ws layout (bf16, [n][k] transposed, zero-padded K tails)
#define OFF_W0T   0          // [256][64]
#define OFF_WHT   16384      // 4 x [256][256]
#define OFF_W5AT  278528     // [256][256]
#define OFF_W5BT  344064     // [256][64]
#define OFF_W6T   360448     // [256][256]
#define OFF_W7T   425984     // [256][256]
#define OFF_WFT   491520     // [256][256]
#define OFF_WMAT  557056     // [128][256]

__global__ void prep_weights(const float* __restrict__ W0, const float* __restrict__ Wh,
                             const float* __restrict__ W5, const float* __restrict__ W6,
                             const float* __restrict__ W7, const float* __restrict__ Wf,
                             const float* __restrict__ Wm, __bf16* __restrict__ ws) {
  int idx = blockIdx.x * blockDim.x + threadIdx.x;
  if (idx >= TOT) return;
  float v = 0.f;
  if (idx < OFF_WHT)        { int j = idx;            int n=j>>6, k=j&63;   v = (k<60)? W0[k*256+n] : 0.f; }
  else if (idx < OFF_W5AT)  { int j = idx - OFF_WHT;  int i=j>>16, r=j&65535, n=r>>8, k=r&255; v = Wh[i*65536+k*256+n]; }
  else if (idx < OFF_W5BT)  { int j = idx - OFF_W5AT; int n=j>>8, k=j&255;  v = W5[k*256+n]; }
  else if (idx < OFF_W6T)   { int j = idx - OFF_W5BT; int n=j>>6, k=j&63;   v = (k<60)? W5[(256+k)*256+n] : 0.f; }
  else if (idx < OFF_W7T)   { int j = idx - OFF_W6T;  int n=j>>8, k=j&255;  v = W6[k*256+n]; }
  else if (idx < OFF_WFT)   { int j = idx - OFF_W7T;  int n=j>>8, k=j&255;  v = W7[k*256+n]; }
  else if (idx < OFF_WMAT)  { int j = idx - OFF_WFT;  int n=j>>8, k=j&255;  v = Wf[k*256+n]; }
  else                      { int j = idx - OFF_WMAT; int n=j>>8, k=j&255;  v = Wm[k*128+n]; }
  __bf16 hi = (__bf16)v;
  ws[idx] = hi;
  ws[TOT + idx] = (__bf16)(v - (float)hi);
}

#define MFMA16(A,B,C) __builtin_amdgcn_mfma_f32_16x16x32_bf16((A),(B),(C),0,0,0)

// ======== M=32 segment layer: proven R3 NT=2 dbuf structure, mt-loop halved ==
// 8 waves, wave covers all 32 rows x its (NT*16)-col slice. Explicit A/B weight
// double-buffer (the ONLY structure that pipelined: compiler pins ~64 arch
// VGPRs in all configs; R5/R8 single-buffer variants exposed full L2 latency,
// R6/R7 NT=4 dbuf spilled 487 MB). Live set here: acc 16 AGPR + wdbuf 32 +
// act 16 + addr ~12 = ~60 arch + 16 agpr -> fits 6 waves/SIMD budget (512/6=85).
// Per-element accumulation order: kc ascending; a_h*b_h, a_h*b_l, a_l*b_h
// -> bit-identical to all prior versions.
template<int NT>
__device__ __forceinline__ void layer_seg(__bf16* aHi, __bf16* aLo, const __half* pxh,
    const __bf16* __restrict__ wHi, const __bf16* __restrict__ wLo, int kStr, int nkc,
    const __bf16* __restrict__ xHi, const __bf16* __restrict__ xLo,  // px weights or null
    const float* __restrict__ bias, const float* __restrict__ pdW,
    bool relu, int tid) {
  const int wave = tid >> 6, lane = tid & 63;
  const int lm = lane & 15, kq = lane >> 4;
  const int nBase = wave * (NT * 16);
  f32x4 acc[2][NT];
#pragma unroll
  for (int mt = 0; mt < 2; ++mt)
#pragma unroll
    for (int nt = 0; nt < NT; ++nt)
#pragma unroll
      for (int e = 0; e < 4; ++e) acc[mt][nt][e] = 0.f;

  const int kb0 = kq * 8;
  const int ar = lm * AH + kb0;          // mBase = 0, M = 32

#define MFMA_BLK(BH,BL,A0H,A0L,A1H,A1L)                       \
    _Pragma("unroll")                                         \
    for (int nt = 0; nt < NT; ++nt) {                         \
      acc[0][nt] = MFMA16(A0H, BH[nt], acc[0][nt]);           \
      acc[0][nt] = MFMA16(A0H, BL[nt], acc[0][nt]);           \
      acc[0][nt] = MFMA16(A0L, BH[nt], acc[0][nt]);           \
      acc[1][nt] = MFMA16(A1H, BH[nt], acc[1][nt]);           \
      acc[1][nt] = MFMA16(A1H, BL[nt], acc[1][nt]);           \
      acc[1][nt] = MFMA16(A1L, BH[nt], acc[1][nt]);           \
    }

  if (nkc >= 2) {                              // act part (K = nkc*32, nkc even)
    int wr[NT];
#pragma unroll
    for (int nt = 0; nt < NT; ++nt) wr[nt] = (nBase + nt*16 + lm) * kStr + kb0;
    bf16x8 bhA[NT], blA[NT], bhB[NT], blB[NT];
#pragma unroll
    for (int nt = 0; nt < NT; ++nt) {          // preload weights kc=0 -> A
      bhA[nt] = *(const bf16x8*)(wHi + wr[nt]);
      blA[nt] = *(const bf16x8*)(wLo + wr[nt]);
    }
    for (int kc = 0; kc < nkc; kc += 2) {
#pragma unroll
      for (int nt = 0; nt < NT; ++nt) {        // prefetch weights kc+1 -> B
        bhB[nt] = *(const bf16x8*)(wHi + wr[nt] + (kc+1)*32);
        blB[nt] = *(const bf16x8*)(wLo + wr[nt] + (kc+1)*32);
      }
      {                                        // act kc, MFMA with A
        const int kb = kc * 32;
        bf16x8 a0h = *(const bf16x8*)(aHi + ar + kb);
        bf16x8 a0l = *(const bf16x8*)(aLo + ar + kb);
        bf16x8 a1h = *(const bf16x8*)(aHi + ar + 16*AH + kb);
        bf16x8 a1l = *(const bf16x8*)(aLo + ar + 16*AH + kb);
        MFMA_BLK(bhA, blA, a0h, a0l, a1h, a1l)
      }
      if (kc + 2 < nkc) {                      // prefetch weights kc+2 -> A
#pragma unroll
        for (int nt = 0; nt < NT; ++nt) {
          bhA[nt] = *(const bf16x8*)(wHi + wr[nt] + (kc+2)*32);
          blA[nt] = *(const bf16x8*)(wLo + wr[nt] + (kc+2)*32);
        }
      }
      {                                        // act kc+1, MFMA with B
        const int kb = (kc+1) * 32;
        bf16x8 a0h = *(const bf16x8*)(aHi + ar + kb);
        bf16x8 a0l = *(const bf16x8*)(aLo + ar + kb);
        bf16x8 a1h = *(const bf16x8*)(aHi + ar + 16*AH + kb);
        bf16x8 a1l = *(const bf16x8*)(aLo + ar + 16*AH + kb);
        MFMA_BLK(bhB, blB, a0h, a0l, a1h, a1l)
      }
    }
  }
  if (xHi) {                                   // px part, K=64 (zero-padded tail)
#pragma unroll
    for (int kc = 0; kc < 2; ++kc) {
      const int kb = kc * 32;
      bf16x8 bh[NT], bl[NT];
#pragma unroll
      for (int nt = 0; nt < NT; ++nt) {
        const int ro = (nBase + nt*16 + lm)*64 + kb0 + kb;
        bh[nt] = *(const bf16x8*)(xHi + ro);
        bl[nt] = *(const bf16x8*)(xLo + ro);
      }
      bf16x8 ah[2], al[2];
#pragma unroll
      for (int mt = 0; mt < 2; ++mt) {
        const f16x8 pv = *(const f16x8*)((const _Float16*)pxh + (mt*16 + lm)*64 + kb0 + kb);
#pragma unroll
        for (int j = 0; j < 8; ++j) {
          float v = (float)pv[j];
          __bf16 h = (__bf16)v;
          ah[mt][j] = h;
          al[mt][j] = (__bf16)(v - (float)h);
        }
      }
      MFMA_BLK(bh, bl, ah[0], al[0], ah[1], al[1])
    }
  }
#undef MFMA_BLK
  __syncthreads();                 // all reads of act complete
#pragma unroll
  for (int nt = 0; nt < NT; ++nt) {
    const int col = nBase + nt*16 + lm;
    float bv = bias[col] + (pdW ? pdW[col] : 0.f);
#pragma unroll
    for (int mt = 0; mt < 2; ++mt)
#pragma unroll
      for (int r = 0; r < 4; ++r) {
        const int row = mt*16 + kq*4 + r;
        float v = acc[mt][nt][r] + bv;
        if (relu) v = fmaxf(v, 0.f);
        __bf16 h = (__bf16)v;
        aHi[row*AH + col] = h;
        aLo[row*AH + col] = (__bf16)(v - (float)h);
      }
  }
  __syncthreads();
}

// ======== M=128 fallback layer (small-ws path, unchanged) ========
template<int NT>
__device__ __forceinline__ void mfma_layer(__bf16* aHi, __bf16* aLo, const __half* pxh,
    const __bf16* __restrict__ wHi, const __bf16* __restrict__ wLo, int kStr, int nkc,
    const __bf16* __restrict__ xHi, const __bf16* __restrict__ xLo,
    const float* __restrict__ bias, const float* __restrict__ pdW,
    bool relu, int tid) {
  const int wave = tid >> 6, lane = tid & 63;
  const int lm = lane & 15, kq = lane >> 4;
  const int mBase = (wave >> 2) * 64;
  const int nBase = (wave & 3) * (NT * 16);
  f32x4 acc[4][NT];
#pragma unroll
  for (int mt = 0; mt < 4; ++mt)
#pragma unroll
    for (int nt = 0; nt < NT; ++nt)
#pragma unroll
      for (int e = 0; e < 4; ++e) acc[mt][nt][e] = 0.f;

  if (nkc >= 2) {
    for (int kc = 0; kc < nkc; ++kc) {
      const int kb = kc*32 + kq*8;
      bf16x8 ah[4], al[4], bh[NT], bl[NT];
#pragma unroll
      for (int mt = 0; mt < 4; ++mt) {
        const int off = (mBase + mt*16 + lm)*AH + kb;
        ah[mt] = *(const bf16x8*)(aHi + off);
        al[mt] = *(const bf16x8*)(aLo + off);
      }
#pragma unroll
      for (int nt = 0; nt < NT; ++nt) {
        const int ro = (nBase + nt*16 + lm)*kStr + kb;
        bh[nt] = *(const bf16x8*)(wHi + ro);
        bl[nt] = *(const bf16x8*)(wLo + ro);
      }
#pragma unroll
      for (int p = 0; p < 3; ++p)
#pragma unroll
        for (int mt = 0; mt < 4; ++mt)
#pragma unroll
          for (int nt = 0; nt < NT; ++nt)
            acc[mt][nt] = __builtin_amdgcn_mfma_f32_16x16x32_bf16(
                (p == 2) ? al[mt] : ah[mt],
                (p == 1) ? bl[nt] : bh[nt],
                acc[mt][nt], 0, 0, 0);
    }
  }
  if (xHi) {
#pragma unroll
    for (int kc = 0; kc < 2; ++kc) {
      const int kb = kc*32 + kq*8;
      bf16x8 bh[NT], bl[NT];
#pragma unroll
      for (int nt = 0; nt < NT; ++nt) {
        const int ro = (nBase + nt*16 + lm)*64 + kb;
        bh[nt] = *(const bf16x8*)(xHi + ro);
        bl[nt] = *(const bf16x8*)(xLo + ro);
      }
#pragma unroll
      for (int mp = 0; mp < 2; ++mp) {
        bf16x8 ah[2], al[2];
#pragma unroll
        for (int i = 0; i < 2; ++i) {
          const f16x8 pv = *(const f16x8*)((const _Float16*)pxh + (mBase + (2*mp+i)*16 + lm)*64 + kb);
#pragma unroll
          for (int j = 0; j < 8; ++j) {
            float v = (float)pv[j];
            __bf16 h = (__bf16)v;
            ah[i][j] = h;
            al[i][j] = (__bf16)(v - (float)h);
          }
        }
#pragma unroll
        for (int nt = 0; nt < NT; ++nt) {
          acc[2*mp  ][nt] = MFMA16(ah[0], bh[nt], acc[2*mp  ][nt]);
          acc[2*mp+1][nt] = MFMA16(ah[1], bh[nt], acc[2*mp+1][nt]);
          acc[2*mp  ][nt] = MFMA16(ah[0], bl[nt], acc[2*mp  ][nt]);
          acc[2*mp+1][nt] = MFMA16(ah[1], bl[nt], acc[2*mp+1][nt]);
          acc[2*mp  ][nt] = MFMA16(al[0], bh[nt], acc[2*mp  ][nt]);
          acc[2*mp+1][nt] = MFMA16(al[1], bh[nt], acc[2*mp+1][nt]);
        }
      }
    }
  }
  __syncthreads();
#pragma unroll
  for (int mt = 0; mt < 4; ++mt)
#pragma unroll
    for (int nt = 0; nt < NT; ++nt) {
      const int col = nBase + nt*16 + lm;
      float bv = bias[col] + (pdW ? pdW[col] : 0.f);
#pragma unroll
      for (int r = 0; r < 4; ++r) {
        const int row = mBase + mt*16 + kq*4 + r;
        float v = acc[mt][nt][r] + bv;
        if (relu) v = fmaxf(v, 0.f);
        __bf16 h = (__bf16)v;
        aHi[row*AH + col] = h;
        aLo[row*AH + col] = (__bf16)(v - (float)h);
      }
    }
  __syncthreads();
}

// SEG=1: blockIdx = ray*4 + seg, covers samples [seg*32, seg*32+32). M=32,
//        LDS ~41 KB -> 3 blocks/CU = 6 waves/SIMD (vs 2 blocks/45% occ at M=64).
// SEG=0: blockIdx = ray, all 128 samples (small-ws fallback).
template<int SEG>
__global__ __launch_bounds__(512, SEG ? 6 : 4)
void nerf_main(
    const float* __restrict__ ro, const float* __restrict__ rd, const float* __restrict__ tin,
    const float* __restrict__ b0, const float* __restrict__ bh,
    const float* __restrict__ b5, const float* __restrict__ b6,
    const float* __restrict__ b7,
    const float* __restrict__ Wsig, const float* __restrict__ bs,
    const float* __restrict__ bfb,
    const float* __restrict__ Wm, const float* __restrict__ bm,
    const float* __restrict__ Wr, const float* __restrict__ br,
    const __bf16* __restrict__ wsHi, const __bf16* __restrict__ wsLo,
    float* __restrict__ part, float* __restrict__ out) {
  constexpr int M = SEG ? 32 : 128;
  constexpr int PXB = (M*128 > 6144) ? M*128 : 6144;   // pxh (M*64 halves) / red (1536 f32)
  __shared__ __align__(16) __bf16 aHi[M * AH];
  __shared__ __align__(16) __bf16 aLo[M * AH];
  __shared__ __align__(16) unsigned char pxred[PXB];
  __shared__ __align__(16) float  pdBuf[24];
  __shared__ __align__(16) float  pdW[128];
  __shared__ __align__(16) float  tBuf[M + 4];
  __shared__ __align__(16) float  sigBuf[M];
  __shared__ __align__(16) float  rgbBuf[M * 3];

  __half* pxh = (__half*)pxred;
  float*  red = (float*)pxred;         // used after pxh dead (sigma head onward)

  const int blk  = blockIdx.x;
  const int ray  = SEG ? (blk >> 2) : blk;
  const int S    = SEG ? (blk & 3) * 32 : 0;
  const int tid  = threadIdx.x;

  // ---- positional encodings ----
  if (tid < M) {
    const int m = tid;
    float tv = tin[ray*128 + S + m];
    tBuf[m] = tv;
    float xs[3];
#pragma unroll
    for (int c = 0; c < 3; ++c) xs[c] = ro[ray*3 + c] + tv * rd[ray*3 + c];
#pragma unroll
    for (int i = 0; i < 10; ++i)
#pragma unroll
      for (int c = 0; c < 3; ++c) {
        float a = ldexpf(xs[c], i);                 // sin(2^i*pi*x) = sinpi(2^i*x)
        pxh[m*64 + i*6 + c]     = __float2half(sinpif(a));
        pxh[m*64 + i*6 + 3 + c] = __float2half(cospif(a));
      }
#pragma unroll
    for (int j = 60; j < 64; ++j) pxh[m*64 + j] = __float2half(0.f);
  } else if (tid < M + 24) {
    int j = tid - M;
    int i = j / 6, r = j % 6;
    float a = ldexpf(rd[ray*3 + (r % 3)], i);
    pdBuf[j] = (r < 3) ? sinpif(a) : cospif(a);
  } else if (tid == M + 24) {
    tBuf[M] = (S + M < 128) ? tin[ray*128 + S + M] : 0.f;   // next-t for last delta
  }
  __syncthreads();
  if (tid >= 256 && tid < 384) {       // pdW[c] = sum_j pd[j]*Wm[256+j][c]
    int c = tid - 256;
    float s = 0.f;
#pragma unroll
    for (int j = 0; j < 24; ++j) s += pdBuf[j] * Wm[(256 + j)*128 + c];
    pdW[c] = s;
  }
  __syncthreads();

  // ---- trunk ----
  if constexpr (SEG) {
    layer_seg<2>(aHi, aLo, pxh, nullptr, nullptr, 0, 0,
                 wsHi + OFF_W0T, wsLo + OFF_W0T, b0, nullptr, true, tid);
    for (int i = 0; i < 4; ++i)
      layer_seg<2>(aHi, aLo, pxh, wsHi + OFF_WHT + i*65536, wsLo + OFF_WHT + i*65536, 256, 8,
                   nullptr, nullptr, bh + i*256, nullptr, true, tid);
    layer_seg<2>(aHi, aLo, pxh, wsHi + OFF_W5AT, wsLo + OFF_W5AT, 256, 8,
                 wsHi + OFF_W5BT, wsLo + OFF_W5BT, b5, nullptr, true, tid);
    layer_seg<2>(aHi, aLo, pxh, wsHi + OFF_W6T, wsLo + OFF_W6T, 256, 8,
                 nullptr, nullptr, b6, nullptr, true, tid);
    layer_seg<2>(aHi, aLo, pxh, wsHi + OFF_W7T, wsLo + OFF_W7T, 256, 8,
                 nullptr, nullptr, b7, nullptr, true, tid);
  } else {
    mfma_layer<4>(aHi, aLo, pxh, nullptr, nullptr, 0, 0,
                  wsHi + OFF_W0T, wsLo + OFF_W0T, b0, nullptr, true, tid);
    for (int i = 0; i < 4; ++i)
      mfma_layer<4>(aHi, aLo, pxh, wsHi + OFF_WHT + i*65536, wsLo + OFF_WHT + i*65536, 256, 8,
                    nullptr, nullptr, bh + i*256, nullptr, true, tid);
    mfma_layer<4>(aHi, aLo, pxh, wsHi + OFF_W5AT, wsLo + OFF_W5AT, 256, 8,
                  wsHi + OFF_W5BT, wsLo + OFF_W5BT, b5, nullptr, true, tid);
    mfma_layer<4>(aHi, aLo, pxh, wsHi + OFF_W6T, wsLo + OFF_W6T, 256, 8,
                  nullptr, nullptr, b6, nullptr, true, tid);
    mfma_layer<4>(aHi, aLo, pxh, wsHi + OFF_W7T, wsLo + OFF_W7T, 256, 8,
                  nullptr, nullptr, b7, nullptr, true, tid);
  }

  // sigma = relu(h @ Ws + bs)   (pxh now dead -> red)
  {
    constexpr int TPS = 512 / M;       // threads per sample (16 or 4)
    const int m = tid / TPS, q = tid % TPS;
    const int kn = 256 / TPS;
    float s = 0.f;
    for (int k8 = q*kn; k8 < q*kn + kn; k8 += 8) {
      bf16x8 vh = *(const bf16x8*)(aHi + m*AH + k8);
      bf16x8 vl = *(const bf16x8*)(aLo + m*AH + k8);
#pragma unroll
      for (int j = 0; j < 8; ++j) s += ((float)vh[j] + (float)vl[j]) * Wsig[k8 + j];
    }
    red[tid] = s;
    __syncthreads();
    if (tid < M) {
      float sm = bs[0];
#pragma unroll
      for (int j = 0; j < TPS; ++j) sm += red[TPS*tid + j];
      sigBuf[tid] = fmaxf(sm, 0.f);
    }
    __syncthreads();
  }

  // feat = h @ Wf + bf (no relu)
  if constexpr (SEG)
    layer_seg<2>(aHi, aLo, nullptr, wsHi + OFF_WFT, wsLo + OFF_WFT, 256, 8,
                 nullptr, nullptr, bfb, nullptr, false, tid);
  else
    mfma_layer<4>(aHi, aLo, nullptr, wsHi + OFF_WFT, wsLo + OFF_WFT, 256, 8,
                  nullptr, nullptr, bfb, nullptr, false, tid);

  // h2 = relu([feat, pd] @ Wm + bm), N=128 (pd folded via pdW)
  if constexpr (SEG)
    layer_seg<1>(aHi, aLo, nullptr, wsHi + OFF_WMAT, wsLo + OFF_WMAT, 256, 8,
                 nullptr, nullptr, bm, pdW, true, tid);
  else
    mfma_layer<2>(aHi, aLo, nullptr, wsHi + OFF_WMAT, wsLo + OFF_WMAT, 256, 8,
                  nullptr, nullptr, bm, pdW, true, tid);

  // rgb = sigmoid(h2 @ Wr + br)
  {
    constexpr int TPS = 512 / M;
    const int m = tid / TPS, q = tid % TPS;
    const int kn = 128 / TPS;
    float r0s = 0.f, r1s = 0.f, r2s = 0.f;
    for (int k8 = q*kn; k8 < q*kn + kn; k8 += 8) {
      bf16x8 vh = *(const bf16x8*)(aHi + m*AH + k8);
      bf16x8 vl = *(const bf16x8*)(aLo + m*AH + k8);
#pragma unroll
      for (int j = 0; j < 8; ++j) {
        float hv = (float)vh[j] + (float)vl[j];
        r0s += hv * Wr[(k8 + j)*3 + 0];
        r1s += hv * Wr[(k8 + j)*3 + 1];
        r2s += hv * Wr[(k8 + j)*3 + 2];
      }
    }
    red[tid] = r0s; red[512 + tid] = r1s; red[1024 + tid] = r2s;
    __syncthreads();
    if (tid < M) {
#pragma unroll
      for (int c = 0; c < 3; ++c) {
        float sm = br[c];
#pragma unroll
        for (int j = 0; j < TPS; ++j) sm += red[c*512 + TPS*tid + j];
        rgbBuf[tid*3 + c] = 1.f / (1.f + expf(-sm));
      }
    }
    __syncthreads();
  }

  // volume rendering: serial transmittance scan over this block's segment
  if (tid == 0) {
    float T = 1.f, c0 = 0.f, c1 = 0.f, c2 = 0.f, wsum = 0.f;
    for (int m = 0; m < M; ++m) {
      float delta = (S + m < 127) ? (tBuf[m + 1] - tBuf[m]) : 1e8f;
      float e = expf(-sigBuf[m] * delta);
      float w = T * (1.f - e);
      c0 += w * rgbBuf[m*3 + 0];
      c1 += w * rgbBuf[m*3 + 1];
      c2 += w * rgbBuf[m*3 + 2];
      wsum += w;
      T *= e;
    }
    if (SEG) {
      float* p = part + blk*5;
      p[0] = c0; p[1] = c1; p[2] = c2; p[3] = wsum; p[4] = T;
    } else {
      float bg = 1.f - wsum;           // C_BG = (1,1,1)
      out[ray*3 + 0] = c0 + bg;
      out[ray*3 + 1] = c1 + bg;
      out[ray*3 + 2] = c2 + bg;
    }
  }
}

// 4-segment combine: C = sum_s (prod_{j<s} T_j) * C_s ; same factorization as
// the proven 2-segment version, one more product level.
__global__ void combine(const float* __restrict__ part, float* __restrict__ out) {
  int r = blockIdx.x * blockDim.x + threadIdx.x;
  if (r >= 2048) return;
  const float* p = part + (4*r)*5;
  float T = 1.f, c0 = 0.f, c1 = 0.f, c2 = 0.f, wsum = 0.f;
#pragma unroll
  for (int s = 0; s < 4; ++s) {
    c0   += T * p[s*5 + 0];
    c1   += T * p[s*5 + 1];
    c2   += T * p[s*5 + 2];
    wsum += T * p[s*5 + 3];
    T    *= p[s*5 + 4];
  }
  float bg = 1.f - wsum;               // C_BG = (1,1,1)
  out[r*3 + 0] = c0 + bg;
  out[r*3 + 1] = c1 + bg;
  out[r*3 + 2] = c2 + bg;
}

extern "C" void kernel_launch(void* const* d_in, const int* in_sizes, int n_in,
                              void* d_out, int out_size, void* d_ws, size_t ws_size,
                              hipStream_t stream) {
  const float* ro  = (const float*)d_in[0];
  const float* rd  = (const float*)d_in[1];
  const float* t   = (const float*)d_in[2];
  const float* W0  = (const float*)d_in[3];
  const float* b0  = (const float*)d_in[4];
  const float* Wh  = (const float*)d_in[5];
  const float* bh  = (const float*)d_in[6];
  const float* W5  = (const float*)d_in[7];
  const float* b5  = (const float*)d_in[8];
  const float* W6  = (const float*)d_in[9];
  const float* b6  = (const float*)d_in[10];
  const float* W7  = (const float*)d_in[11];
  const float* b7  = (const float*)d_in[12];
  const float* Wsg = (const float*)d_in[13];
  const float* bs  = (const float*)d_in[14];
  const float* Wf  = (const float*)d_in[15];
  const float* bfb = (const float*)d_in[16];
  const float* Wm  = (const float*)d_in[17];
  const float* bm  = (const float*)d_in[18];
  const float* Wr  = (const float*)d_in[19];
  const float* br  = (const float*)d_in[20];
  float* out = (float*)d_out;

  __bf16* wsHi = (__bf16*)d_ws;                     // 2*TOT bf16 = 2.36 MB (proven)
  __bf16* wsLo = wsHi + TOT;
  float*  part = (float*)((char*)d_ws + (size_t)2 * TOT * 2);   // 8192*5 floats = 160 KB

  const size_t needSplit = (size_t)2 * TOT * 2 + (size_t)8192 * 5 * 4;

  prep_weights<<<(TOT + 255)/256, 256, 0, stream>>>(W0, Wh, W5, W6, W7, Wf, Wm, wsHi);
  if (ws_size >= needSplit) {
    nerf_main<1><<<8192, 512, 0, stream>>>(ro, rd, t, b0, bh, b5, b6, b7,
                                           Wsg, bs, bfb, Wm, bm, Wr, br,
                                           wsHi, wsLo, part, out);
    combine<<<8, 256, 0, stream>>>(part, out);
  } else {
    nerf_main<0><<<2048, 512, 0, stream>>>(ro, rd, t, b0, bh, b5, b6, b7,
                                           Wsg, bs, bfb, Wm, bm, Wr, br,
                                           wsHi, wsLo, part, out);
  }
}

// Round 10
// 1255.437 us; speedup vs baseline: 1.8860x; 1.7315x over previous
//
#include <hip/hip_runtime.h>
#include <hip/hip_fp16.h>
#include <math.h>

typedef __bf16   bf16x8 __attribute__((ext_vector_type(8)));
typedef _Float16 f16x8  __attribute__((ext_vector_type(8)));
typedef float    f32x4  __attribute__((ext_vector_type(4)));

#define AH  264              // act plane stride (bf16)
#define TOT 589824           // staged weight elems (hi); lo at +TOT

// staged ws layout (bf16, [n][k] transposed, zero-padded K tails)
#define OFF_W0T   0          // [256][64]
#define OFF_WHT   16384      // 4 x [256][256]
#define OFF_W5AT  278528     // [256][256]
#define OFF_W5BT  344064     // [256][64]
#define OFF_W6T   360448     // [256][256]
#define OFF_W7T   425984     // [256][256]
#define OFF_WFT   491520     // [256][256]
#define OFF_WMAT  557056     // [128][256]

__global__ void prep_weights(const float* __restrict__ W0, const float* __restrict__ Wh,
                             const float* __restrict__ W5, const float* __restrict__ W6,
                             const float* __restrict__ W7, const float* __restrict__ Wf,
                             const float* __restrict__ Wm, __bf16* __restrict__ ws) {
  int idx = blockIdx.x * blockDim.x + threadIdx.x;
  if (idx >= TOT) return;
  float v = 0.f;
  if (idx < OFF_WHT)        { int j = idx;            int n=j>>6, k=j&63;   v = (k<60)? W0[k*256+n] : 0.f; }
  else if (idx < OFF_W5AT)  { int j = idx - OFF_WHT;  int i=j>>16, r=j&65535, n=r>>8, k=r&255; v = Wh[i*65536+k*256+n]; }
  else if (idx < OFF_W5BT)  { int j = idx - OFF_W5AT; int n=j>>8, k=j&255;  v = W5[k*256+n]; }
  else if (idx < OFF_W6T)   { int j = idx - OFF_W5BT; int n=j>>6, k=j&63;   v = (k<60)? W5[(256+k)*256+n] : 0.f; }
  else if (idx < OFF_W7T)   { int j = idx - OFF_W6T;  int n=j>>8, k=j&255;  v = W6[k*256+n]; }
  else if (idx < OFF_WFT)   { int j = idx - OFF_W7T;  int n=j>>8, k=j&255;  v = W7[k*256+n]; }
  else if (idx < OFF_WMAT)  { int j = idx - OFF_WFT;  int n=j>>8, k=j&255;  v = Wf[k*256+n]; }
  else                      { int j = idx - OFF_WMAT; int n=j>>8, k=j&255;  v = Wm[k*128+n]; }
  __bf16 hi = (__bf16)v;
  ws[idx] = hi;
  ws[TOT + idx] = (__bf16)(v - (float)hi);
}

#define MFMA16(A,B,C) __builtin_amdgcn_mfma_f32_16x16x32_bf16((A),(B),(C),0,0,0)

// ---- split-bf16 3-pass MFMA layer; act = hi/lo bf16 planes in LDS ----
// EXACT R3 structure (best measured: 1271 us): 512 threads = 8 waves, 4 m-tiles
// per wave, HALF=1: M=64, mBase=0, nBase=wave*(NT*16). NT<=2 path: explicit A/B
// weight double-buffer -- the ONLY structure that pipelines within the
// compiler's ~64-arch-VGPR allocation (session ledger: no-dbuf R5/R8 exposed
// full L2 latency; NT=4 dbuf R6/R7 spilled 487 MB; M=32 R9 doubled the
// fixed-latency fraction). Added vs R3: s_setprio(1) around MFMA clusters --
// 2 independent blocks/CU at different phases is the regime where setprio pays
// (attn +4-7% m191), not the lockstep-null regime (m190).
// Accumulation order per acc element: kc ascending; a_h*b_h, a_h*b_l, a_l*b_h
// -> bit-identical numerics to all prior versions.
template<int NT, int HALF>
__device__ __forceinline__ void mfma_layer(__bf16* aHi, __bf16* aLo, const __half* pxh,
    const __bf16* __restrict__ wHi, const __bf16* __restrict__ wLo, int kStr, int nkc,
    const __bf16* __restrict__ xHi, const __bf16* __restrict__ xLo,  // px weights or null
    const float* __restrict__ bias, const float* __restrict__ pdW,
    bool relu, int tid) {
  const int wave = tid >> 6, lane = tid & 63;
  const int lm = lane & 15, kq = lane >> 4;
  const int mBase = HALF ? 0 : (wave >> 2) * 64;
  const int nBase = (HALF ? wave : (wave & 3)) * (NT * 16);
  f32x4 acc[4][NT];
#pragma unroll
  for (int mt = 0; mt < 4; ++mt)
#pragma unroll
    for (int nt = 0; nt < NT; ++nt)
#pragma unroll
      for (int e = 0; e < 4; ++e) acc[mt][nt][e] = 0.f;

  if (nkc >= 2) {                              // act part (K = nkc*32, nkc always even)
    if constexpr (NT <= 2) {
      const int kb0 = kq * 8;
      int wr[NT];
#pragma unroll
      for (int nt = 0; nt < NT; ++nt) wr[nt] = (nBase + nt*16 + lm)*kStr + kb0;
      const int ab = (mBase + lm)*AH + kb0;
      bf16x8 bhA[NT], blA[NT], bhB[NT], blB[NT];
#pragma unroll
      for (int nt = 0; nt < NT; ++nt) {        // preload kc=0
        bhA[nt] = *(const bf16x8*)(wHi + wr[nt]);
        blA[nt] = *(const bf16x8*)(wLo + wr[nt]);
      }
      for (int kc = 0; kc < nkc; kc += 2) {
        // prefetch kc+1 weights into B while A computes
#pragma unroll
        for (int nt = 0; nt < NT; ++nt) {
          bhB[nt] = *(const bf16x8*)(wHi + wr[nt] + (kc+1)*32);
          blB[nt] = *(const bf16x8*)(wLo + wr[nt] + (kc+1)*32);
        }
#pragma unroll
        for (int mp = 0; mp < 2; ++mp) {       // compute kc with A
          const int r0 = ab + mp*32*AH + kc*32;
          bf16x8 a0h = *(const bf16x8*)(aHi + r0);
          bf16x8 a0l = *(const bf16x8*)(aLo + r0);
          bf16x8 a1h = *(const bf16x8*)(aHi + r0 + 16*AH);
          bf16x8 a1l = *(const bf16x8*)(aLo + r0 + 16*AH);
          __builtin_amdgcn_s_setprio(1);
#pragma unroll
          for (int nt = 0; nt < NT; ++nt) {
            acc[2*mp  ][nt] = MFMA16(a0h, bhA[nt], acc[2*mp  ][nt]);
            acc[2*mp+1][nt] = MFMA16(a1h, bhA[nt], acc[2*mp+1][nt]);
            acc[2*mp  ][nt] = MFMA16(a0h, blA[nt], acc[2*mp  ][nt]);
            acc[2*mp+1][nt] = MFMA16(a1h, blA[nt], acc[2*mp+1][nt]);
            acc[2*mp  ][nt] = MFMA16(a0l, bhA[nt], acc[2*mp  ][nt]);
            acc[2*mp+1][nt] = MFMA16(a1l, bhA[nt], acc[2*mp+1][nt]);
          }
          __builtin_amdgcn_s_setprio(0);
        }
        if (kc + 2 < nkc) {                    // prefetch kc+2 into A
#pragma unroll
          for (int nt = 0; nt < NT; ++nt) {
            bhA[nt] = *(const bf16x8*)(wHi + wr[nt] + (kc+2)*32);
            blA[nt] = *(const bf16x8*)(wLo + wr[nt] + (kc+2)*32);
          }
        }
#pragma unroll
        for (int mp = 0; mp < 2; ++mp) {       // compute kc+1 with B
          const int r0 = ab + mp*32*AH + (kc+1)*32;
          bf16x8 a0h = *(const bf16x8*)(aHi + r0);
          bf16x8 a0l = *(const bf16x8*)(aLo + r0);
          bf16x8 a1h = *(const bf16x8*)(aHi + r0 + 16*AH);
          bf16x8 a1l = *(const bf16x8*)(aLo + r0 + 16*AH);
          __builtin_amdgcn_s_setprio(1);
#pragma unroll
          for (int nt = 0; nt < NT; ++nt) {
            acc[2*mp  ][nt] = MFMA16(a0h, bhB[nt], acc[2*mp  ][nt]);
            acc[2*mp+1][nt] = MFMA16(a1h, bhB[nt], acc[2*mp+1][nt]);
            acc[2*mp  ][nt] = MFMA16(a0h, blB[nt], acc[2*mp  ][nt]);
            acc[2*mp+1][nt] = MFMA16(a1h, blB[nt], acc[2*mp+1][nt]);
            acc[2*mp  ][nt] = MFMA16(a0l, bhB[nt], acc[2*mp  ][nt]);
            acc[2*mp+1][nt] = MFMA16(a1l, bhB[nt], acc[2*mp+1][nt]);
          }
          __builtin_amdgcn_s_setprio(0);
        }
      }
    } else {                                   // NT=4 fallback (unused in HALF=1 runs)
      for (int kc = 0; kc < nkc; ++kc) {
        const int kb = kc*32 + kq*8;
        bf16x8 ah[4], al[4], bh[NT], bl[NT];
#pragma unroll
        for (int mt = 0; mt < 4; ++mt) {
          const int off = (mBase + mt*16 + lm)*AH + kb;
          ah[mt] = *(const bf16x8*)(aHi + off);
          al[mt] = *(const bf16x8*)(aLo + off);
        }
#pragma unroll
        for (int nt = 0; nt < NT; ++nt) {
          const int ro = (nBase + nt*16 + lm)*kStr + kb;
          bh[nt] = *(const bf16x8*)(wHi + ro);
          bl[nt] = *(const bf16x8*)(wLo + ro);
        }
#pragma unroll
        for (int p = 0; p < 3; ++p)
#pragma unroll
          for (int mt = 0; mt < 4; ++mt)
#pragma unroll
            for (int nt = 0; nt < NT; ++nt)
              acc[mt][nt] = __builtin_amdgcn_mfma_f32_16x16x32_bf16(
                  (p == 2) ? al[mt] : ah[mt],
                  (p == 1) ? bl[nt] : bh[nt],
                  acc[mt][nt], 0, 0, 0);
      }
    }
  }
  if (xHi) {                                   // px part, K=64 (zero-padded tail)
#pragma unroll
    for (int kc = 0; kc < 2; ++kc) {
      const int kb = kc*32 + kq*8;
      bf16x8 bh[NT], bl[NT];
#pragma unroll
      for (int nt = 0; nt < NT; ++nt) {
        const int ro = (nBase + nt*16 + lm)*64 + kb;
        bh[nt] = *(const bf16x8*)(xHi + ro);
        bl[nt] = *(const bf16x8*)(xLo + ro);
      }
#pragma unroll
      for (int mp = 0; mp < 2; ++mp) {
        bf16x8 ah[2], al[2];
#pragma unroll
        for (int i = 0; i < 2; ++i) {          // vector f16 LDS read
          const f16x8 pv = *(const f16x8*)((const _Float16*)pxh + (mBase + (2*mp+i)*16 + lm)*64 + kb);
#pragma unroll
          for (int j = 0; j < 8; ++j) {
            float v = (float)pv[j];
            __bf16 h = (__bf16)v;
            ah[i][j] = h;
            al[i][j] = (__bf16)(v - (float)h);
          }
        }
        __builtin_amdgcn_s_setprio(1);
#pragma unroll
        for (int nt = 0; nt < NT; ++nt) {
          acc[2*mp  ][nt] = MFMA16(ah[0], bh[nt], acc[2*mp  ][nt]);
          acc[2*mp+1][nt] = MFMA16(ah[1], bh[nt], acc[2*mp+1][nt]);
          acc[2*mp  ][nt] = MFMA16(ah[0], bl[nt], acc[2*mp  ][nt]);
          acc[2*mp+1][nt] = MFMA16(ah[1], bl[nt], acc[2*mp+1][nt]);
          acc[2*mp  ][nt] = MFMA16(al[0], bh[nt], acc[2*mp  ][nt]);
          acc[2*mp+1][nt] = MFMA16(al[1], bh[nt], acc[2*mp+1][nt]);
        }
        __builtin_amdgcn_s_setprio(0);
      }
    }
  }
  __syncthreads();                 // all reads of act complete
#pragma unroll
  for (int mt = 0; mt < 4; ++mt)
#pragma unroll
    for (int nt = 0; nt < NT; ++nt) {
      const int col = nBase + nt*16 + lm;
      float bv = bias[col] + (pdW ? pdW[col] : 0.f);
#pragma unroll
      for (int r = 0; r < 4; ++r) {
        const int row = mBase + mt*16 + kq*4 + r;
        float v = acc[mt][nt][r] + bv;
        if (relu) v = fmaxf(v, 0.f);
        __bf16 h = (__bf16)v;
        aHi[row*AH + col] = h;
        aLo[row*AH + col] = (__bf16)(v - (float)h);
      }
    }
  __syncthreads();
}

// HALF=1: blockIdx = ray*2 + half, covers samples [half*64, half*64+64)
// HALF=0: blockIdx = ray, covers all 128 samples (fallback config)
template<int HALF>
__global__ __launch_bounds__(512, 4)
void nerf_main(
    const float* __restrict__ ro, const float* __restrict__ rd, const float* __restrict__ tin,
    const float* __restrict__ b0, const float* __restrict__ bh,
    const float* __restrict__ b5, const float* __restrict__ b6,
    const float* __restrict__ b7,
    const float* __restrict__ Wsig, const float* __restrict__ bs,
    const float* __restrict__ bfb,
    const float* __restrict__ Wm, const float* __restrict__ bm,
    const float* __restrict__ Wr, const float* __restrict__ br,
    const __bf16* __restrict__ wsHi, const __bf16* __restrict__ wsLo,
    float* __restrict__ part, float* __restrict__ out) {
  constexpr int M = HALF ? 64 : 128;
  __shared__ __align__(16) __bf16 aHi[M * AH];
  __shared__ __align__(16) __bf16 aLo[M * AH];
  __shared__ __align__(16) unsigned char pxred[M * 128];  // pxh (M*64 halves) / red union
  __shared__ __align__(16) float  pdBuf[24];
  __shared__ __align__(16) float  pdW[128];
  __shared__ __align__(16) float  tBuf[M + 4];
  __shared__ __align__(16) float  sigBuf[M];
  __shared__ __align__(16) float  rgbBuf[M * 3];

  __half* pxh = (__half*)pxred;
  float*  red = (float*)pxred;         // used after pxh dead (sigma head onward)

  const int blk  = blockIdx.x;
  const int ray  = HALF ? (blk >> 1) : blk;
  const int S    = HALF ? (blk & 1) * 64 : 0;
  const int tid  = threadIdx.x;

  // ---- positional encodings ----
  if (tid < M) {
    const int m = tid;
    float tv = tin[ray*128 + S + m];
    tBuf[m] = tv;
    float xs[3];
#pragma unroll
    for (int c = 0; c < 3; ++c) xs[c] = ro[ray*3 + c] + tv * rd[ray*3 + c];
#pragma unroll
    for (int i = 0; i < 10; ++i)
#pragma unroll
      for (int c = 0; c < 3; ++c) {
        float a = ldexpf(xs[c], i);                 // sin(2^i*pi*x) = sinpi(2^i*x)
        pxh[m*64 + i*6 + c]     = __float2half(sinpif(a));
        pxh[m*64 + i*6 + 3 + c] = __float2half(cospif(a));
      }
#pragma unroll
    for (int j = 60; j < 64; ++j) pxh[m*64 + j] = __float2half(0.f);
  } else if (tid < M + 24) {
    int j = tid - M;
    int i = j / 6, r = j % 6;
    float a = ldexpf(rd[ray*3 + (r % 3)], i);
    pdBuf[j] = (r < 3) ? sinpif(a) : cospif(a);
  } else if (tid == M + 24) {
    tBuf[M] = (S + M < 128) ? tin[ray*128 + S + M] : 0.f;   // next-t for last delta
  }
  __syncthreads();
  if (tid >= 256 && tid < 384) {       // pdW[c] = sum_j pd[j]*Wm[256+j][c]
    int c = tid - 256;
    float s = 0.f;
#pragma unroll
    for (int j = 0; j < 24; ++j) s += pdBuf[j] * Wm[(256 + j)*128 + c];
    pdW[c] = s;
  }
  __syncthreads();

  constexpr int NTF = HALF ? 2 : 4;    // full layers (N=256)
  constexpr int NTW = HALF ? 1 : 2;    // Wm layer (N=128)

  // ---- trunk ----
  mfma_layer<NTF, HALF>(aHi, aLo, pxh, nullptr, nullptr, 0, 0,
                        wsHi + OFF_W0T, wsLo + OFF_W0T, b0, nullptr, true, tid);
  for (int i = 0; i < 4; ++i)
    mfma_layer<NTF, HALF>(aHi, aLo, pxh, wsHi + OFF_WHT + i*65536, wsLo + OFF_WHT + i*65536, 256, 8,
                          nullptr, nullptr, bh + i*256, nullptr, true, tid);
  mfma_layer<NTF, HALF>(aHi, aLo, pxh, wsHi + OFF_W5AT, wsLo + OFF_W5AT, 256, 8,
                        wsHi + OFF_W5BT, wsLo + OFF_W5BT, b5, nullptr, true, tid);
  mfma_layer<NTF, HALF>(aHi, aLo, pxh, wsHi + OFF_W6T, wsLo + OFF_W6T, 256, 8,
                        nullptr, nullptr, b6, nullptr, true, tid);
  mfma_layer<NTF, HALF>(aHi, aLo, pxh, wsHi + OFF_W7T, wsLo + OFF_W7T, 256, 8,
                        nullptr, nullptr, b7, nullptr, true, tid);

  // sigma = relu(h @ Ws + bs)   (pxh now dead -> red)
  {
    constexpr int TPS = 512 / M;       // threads per sample (8 or 4)
    const int m = tid / TPS, q = tid % TPS;
    const int kn = 256 / TPS;
    float s = 0.f;
    for (int k8 = q*kn; k8 < q*kn + kn; k8 += 8) {
      bf16x8 vh = *(const bf16x8*)(aHi + m*AH + k8);
      bf16x8 vl = *(const bf16x8*)(aLo + m*AH + k8);
#pragma unroll
      for (int j = 0; j < 8; ++j) s += ((float)vh[j] + (float)vl[j]) * Wsig[k8 + j];
    }
    red[tid] = s;
    __syncthreads();
    if (tid < M) {
      float sm = bs[0];
#pragma unroll
      for (int j = 0; j < TPS; ++j) sm += red[TPS*tid + j];
      sigBuf[tid] = fmaxf(sm, 0.f);
    }
    __syncthreads();
  }

  // feat = h @ Wf + bf (no relu)
  mfma_layer<NTF, HALF>(aHi, aLo, nullptr, wsHi + OFF_WFT, wsLo + OFF_WFT, 256, 8,
                        nullptr, nullptr, bfb, nullptr, false, tid);

  // h2 = relu([feat, pd] @ Wm + bm), N=128 (pd folded via pdW)
  mfma_layer<NTW, HALF>(aHi, aLo, nullptr, wsHi + OFF_WMAT, wsLo + OFF_WMAT, 256, 8,
                        nullptr, nullptr, bm, pdW, true, tid);

  // rgb = sigmoid(h2 @ Wr + br)
  {
    constexpr int TPS = 512 / M;
    const int m = tid / TPS, q = tid % TPS;
    const int kn = 128 / TPS;
    float r0s = 0.f, r1s = 0.f, r2s = 0.f;
    for (int k8 = q*kn; k8 < q*kn + kn; k8 += 8) {
      bf16x8 vh = *(const bf16x8*)(aHi + m*AH + k8);
      bf16x8 vl = *(const bf16x8*)(aLo + m*AH + k8);
#pragma unroll
      for (int j = 0; j < 8; ++j) {
        float hv = (float)vh[j] + (float)vl[j];
        r0s += hv * Wr[(k8 + j)*3 + 0];
        r1s += hv * Wr[(k8 + j)*3 + 1];
        r2s += hv * Wr[(k8 + j)*3 + 2];
      }
    }
    red[tid] = r0s; red[512 + tid] = r1s; red[1024 + tid] = r2s;
    __syncthreads();
    if (tid < M) {
#pragma unroll
      for (int c = 0; c < 3; ++c) {
        float sm = br[c];
#pragma unroll
        for (int j = 0; j < TPS; ++j) sm += red[c*512 + TPS*tid + j];
        rgbBuf[tid*3 + c] = 1.f / (1.f + expf(-sm));
      }
    }
    __syncthreads();
  }

  // volume rendering: serial transmittance scan over this block's segment
  if (tid == 0) {
    float T = 1.f, c0 = 0.f, c1 = 0.f, c2 = 0.f, wsum = 0.f;
    for (int m = 0; m < M; ++m) {
      float delta = (S + m < 127) ? (tBuf[m + 1] - tBuf[m]) : 1e8f;
      float e = expf(-sigBuf[m] * delta);
      float w = T * (1.f - e);
      c0 += w * rgbBuf[m*3 + 0];
      c1 += w * rgbBuf[m*3 + 1];
      c2 += w * rgbBuf[m*3 + 2];
      wsum += w;
      T *= e;
    }
    if (HALF) {
      float* p = part + blk*5;
      p[0] = c0; p[1] = c1; p[2] = c2; p[3] = wsum; p[4] = T;
    } else {
      float bg = 1.f - wsum;           // C_BG = (1,1,1)
      out[ray*3 + 0] = c0 + bg;
      out[ray*3 + 1] = c1 + bg;
      out[ray*3 + 2] = c2 + bg;
    }
  }
}

__global__ void combine(const float* __restrict__ part, float* __restrict__ out) {
  int r = blockIdx.x * blockDim.x + threadIdx.x;
  if (r >= 2048) return;
  const float* p0 = part + (2*r)*5;
  const float* p1 = p0 + 5;
  float T0 = p0[4];
  float wsum = p0[3] + T0 * p1[3];
  float bg = 1.f - wsum;               // C_BG = (1,1,1)
#pragma unroll
  for (int c = 0; c < 3; ++c)
    out[r*3 + c] = p0[c] + T0 * p1[c] + bg;
}

extern "C" void kernel_launch(void* const* d_in, const int* in_sizes, int n_in,
                              void* d_out, int out_size, void* d_ws, size_t ws_size,
                              hipStream_t stream) {
  const float* ro  = (const float*)d_in[0];
  const float* rd  = (const float*)d_in[1];
  const float* t   = (const float*)d_in[2];
  const float* W0  = (const float*)d_in[3];
  const float* b0  = (const float*)d_in[4];
  const float* Wh  = (const float*)d_in[5];
  const float* bh  = (const float*)d_in[6];
  const float* W5  = (const float*)d_in[7];
  const float* b5  = (const float*)d_in[8];
  const float* W6  = (const float*)d_in[9];
  const float* b6  = (const float*)d_in[10];
  const float* W7  = (const float*)d_in[11];
  const float* b7  = (const float*)d_in[12];
  const float* Wsg = (const float*)d_in[13];
  const float* bs  = (const float*)d_in[14];
  const float* Wf  = (const float*)d_in[15];
  const float* bfb = (const float*)d_in[16];
  const float* Wm  = (const float*)d_in[17];
  const float* bm  = (const float*)d_in[18];
  const float* Wr  = (const float*)d_in[19];
  const float* br  = (const float*)d_in[20];
  float* out = (float*)d_out;

  __bf16* wsHi = (__bf16*)d_ws;                     // 2*TOT bf16 = 2.36 MB (proven)
  __bf16* wsLo = wsHi + TOT;
  float*  part = (float*)((char*)d_ws + (size_t)2 * TOT * 2);   // 4096*5 floats = 80 KB

  const size_t needSplit = (size_t)2 * TOT * 2 + (size_t)4096 * 5 * 4;

  prep_weights<<<(TOT + 255)/256, 256, 0, stream>>>(W0, Wh, W5, W6, W7, Wf, Wm, wsHi);
  if (ws_size >= needSplit) {
    nerf_main<1><<<4096, 512, 0, stream>>>(ro, rd, t, b0, bh, b5, b6, b7,
                                           Wsg, bs, bfb, Wm, bm, Wr, br,
                                           wsHi, wsLo, part, out);
    combine<<<8, 256, 0, stream>>>(part, out);
  } else {
    nerf_main<0><<<2048, 512, 0, stream>>>(ro, rd, t, b0, bh, b5, b6, b7,
                                           Wsg, bs, bfb, Wm, bm, Wr, br,
                                           wsHi, wsLo, part, out);
  }
}